// Round 12
// baseline (363.421 us; speedup 1.0000x reference)
//
#include <hip/hip_runtime.h>
#include <hip/hip_bf16.h>

#define BN_EPS 1e-5f
#define NB 64
#define NN 1000
#define NP 1024
#define HD 128
#define CS 8
#define NC 125  // NN/CS exactly

typedef short bf16x8 __attribute__((ext_vector_type(8)));
typedef float f32x4 __attribute__((ext_vector_type(4)));

__device__ __forceinline__ unsigned short f2b(float f) {
  __hip_bfloat16 h = __float2bfloat16(f);
  return *reinterpret_cast<unsigned short*>(&h);
}
__device__ __forceinline__ float b2f(unsigned short u) {
  unsigned v = ((unsigned)u) << 16;
  return __uint_as_float(v);
}
// monotonic float -> uint (unsigned compare == float compare)
__device__ __forceinline__ unsigned tkey(float f) {
  unsigned u = __float_as_uint(f);
  return u ^ ((unsigned)((int)u >> 31) | 0x80000000u);
}
__device__ __forceinline__ float tdec(unsigned m) {
  unsigned u = (m & 0x80000000u) ? (m ^ 0x80000000u) : ~m;
  return __uint_as_float(u);
}

// ---------------------------------------------------------------------------
// Embedding MLP, register-tiled. 64 nodes/block. Writes xb (bf16).
// Blocks 0..191 also transpose the 3 GAT weights into WT (bf16).
// ---------------------------------------------------------------------------
__global__ __launch_bounds__(256) void k_embed(
    const float* __restrict__ locs,
    const float* __restrict__ W0, const float* __restrict__ b0,
    const float* __restrict__ W1, const float* __restrict__ b1,
    const float* __restrict__ g1, const float* __restrict__ be1,
    const float* __restrict__ m1, const float* __restrict__ v1,
    const float* __restrict__ Wo, const float* __restrict__ bo,
    const float* __restrict__ gatW, unsigned short* __restrict__ WT,
    unsigned short* __restrict__ xb) {
  __shared__ float z1T[64][68];
  __shared__ float z2T[64][68];
  int tid = threadIdx.x;
  long base = (long)blockIdx.x * 64;

  if (blockIdx.x < 192) {  // fused W transpose: 49152 elems
    int idx = blockIdx.x * 256 + tid;
    int lay = idx >> 14, rem = idx & 16383;
    int n = rem >> 7, kk = rem & 127;
    WT[idx] = f2b(gatW[lay * 16384 + kk * 128 + n]);
  }

  {
    int d = tid & 63;
    int q = tid >> 6;
    float w0x = W0[d], w0y = W0[64 + d], bb = b0[d];
#pragma unroll
    for (int g = 0; g < 4; ++g) {
      float vv[4];
#pragma unroll
      for (int i = 0; i < 4; ++i) {
        int n = g * 16 + q * 4 + i;
        float lx = locs[(base + n) * 2 + 0];
        float ly = locs[(base + n) * 2 + 1];
        vv[i] = fmaxf(fmaf(lx, w0x, fmaf(ly, w0y, bb)), 0.f);
      }
      *(float4*)&z1T[d][g * 16 + q * 4] = make_float4(vv[0], vv[1], vv[2], vv[3]);
    }
  }
  __syncthreads();

  int nt = tid & 15;
  int dt = tid >> 4;

  {
    float acc[4][4];
#pragma unroll
    for (int i = 0; i < 4; ++i)
#pragma unroll
      for (int j = 0; j < 4; ++j) acc[i][j] = 0.f;
#pragma unroll 4
    for (int k = 0; k < 64; ++k) {
      float4 zv = *(const float4*)&z1T[k][4 * nt];
      float4 wv = *(const float4*)&W1[k * 64 + 4 * dt];
      float zz[4] = {zv.x, zv.y, zv.z, zv.w};
      float ww[4] = {wv.x, wv.y, wv.z, wv.w};
#pragma unroll
      for (int i = 0; i < 4; ++i)
#pragma unroll
        for (int j = 0; j < 4; ++j) acc[i][j] = fmaf(zz[i], ww[j], acc[i][j]);
    }
    float4 b1v = *(const float4*)&b1[4 * dt];
    float4 g1v = *(const float4*)&g1[4 * dt];
    float4 bev = *(const float4*)&be1[4 * dt];
    float4 m1v = *(const float4*)&m1[4 * dt];
    float4 v1v = *(const float4*)&v1[4 * dt];
    float bbv[4] = {b1v.x, b1v.y, b1v.z, b1v.w};
    float ggv[4] = {g1v.x, g1v.y, g1v.z, g1v.w};
    float eev[4] = {bev.x, bev.y, bev.z, bev.w};
    float mmv[4] = {m1v.x, m1v.y, m1v.z, m1v.w};
    float vvv[4] = {v1v.x, v1v.y, v1v.z, v1v.w};
#pragma unroll
    for (int j = 0; j < 4; ++j) {
      float sc = ggv[j] * rsqrtf(vvv[j] + BN_EPS);
      float sh = eev[j] - mmv[j] * sc;
      float o[4];
#pragma unroll
      for (int i = 0; i < 4; ++i)
        o[i] = fmaxf(fmaf(acc[i][j] + bbv[j], sc, sh), 0.f);
      *(float4*)&z2T[4 * dt + j][4 * nt] = make_float4(o[0], o[1], o[2], o[3]);
    }
  }
  __syncthreads();

  {
    float acc[4][8];
#pragma unroll
    for (int i = 0; i < 4; ++i)
#pragma unroll
      for (int j = 0; j < 8; ++j) acc[i][j] = 0.f;
#pragma unroll 2
    for (int k = 0; k < 64; ++k) {
      float4 zv = *(const float4*)&z2T[k][4 * nt];
      float4 wa = *(const float4*)&Wo[k * 128 + 4 * dt];
      float4 wb = *(const float4*)&Wo[k * 128 + 64 + 4 * dt];
      float zz[4] = {zv.x, zv.y, zv.z, zv.w};
      float w0[4] = {wa.x, wa.y, wa.z, wa.w};
      float w1[4] = {wb.x, wb.y, wb.z, wb.w};
#pragma unroll
      for (int i = 0; i < 4; ++i) {
#pragma unroll
        for (int j = 0; j < 4; ++j) {
          acc[i][j] = fmaf(zz[i], w0[j], acc[i][j]);
          acc[i][4 + j] = fmaf(zz[i], w1[j], acc[i][4 + j]);
        }
      }
    }
    float4 bo0 = *(const float4*)&bo[4 * dt];
    float4 bo1 = *(const float4*)&bo[64 + 4 * dt];
    float bb0[4] = {bo0.x, bo0.y, bo0.z, bo0.w};
    float bb1[4] = {bo1.x, bo1.y, bo1.z, bo1.w};
#pragma unroll
    for (int i = 0; i < 4; ++i) {
      ushort4 p0, p1;
      p0.x = f2b(acc[i][0] + bb0[0]); p0.y = f2b(acc[i][1] + bb0[1]);
      p0.z = f2b(acc[i][2] + bb0[2]); p0.w = f2b(acc[i][3] + bb0[3]);
      p1.x = f2b(acc[i][4] + bb1[0]); p1.y = f2b(acc[i][5] + bb1[1]);
      p1.z = f2b(acc[i][6] + bb1[2]); p1.w = f2b(acc[i][7] + bb1[3]);
      *(ushort4*)&xb[(base + 4 * nt + i) * 128 + 4 * dt] = p0;
      *(ushort4*)&xb[(base + 4 * nt + i) * 128 + 64 + 4 * dt] = p1;
    }
  }
}

// ---------------------------------------------------------------------------
// h = xb @ W via MFMA 16x16x32 bf16. No LDS. Block = 4 waves, wave = 16 rows.
// Writes hb (bf16); e_src/e_dst dots from f32 accumulators.
// ---------------------------------------------------------------------------
__global__ __launch_bounds__(256) void k_gemm_e(
    const unsigned short* __restrict__ xb, const unsigned short* __restrict__ WT,
    const float* __restrict__ asrc, const float* __restrict__ adst,
    unsigned short* __restrict__ hb, float* __restrict__ es,
    float* __restrict__ ed) {
  int tid = threadIdx.x;
  int w = tid >> 6, l = tid & 63;
  long rowbase = (long)blockIdx.x * 64 + w * 16;
  int r = l & 15, g = l >> 4;

  f32x4 acc[8];
#pragma unroll
  for (int n = 0; n < 8; ++n) acc[n] = {0.f, 0.f, 0.f, 0.f};

#pragma unroll
  for (int ks = 0; ks < 4; ++ks) {
    bf16x8 a = *(const bf16x8*)&xb[(rowbase + r) * 128 + ks * 32 + g * 8];
#pragma unroll
    for (int n = 0; n < 8; ++n) {
      bf16x8 bfr = *(const bf16x8*)&WT[(n * 16 + r) * 128 + ks * 32 + g * 8];
      acc[n] = __builtin_amdgcn_mfma_f32_16x16x32_bf16(a, bfr, acc[n], 0, 0, 0);
    }
  }

  float ps[4] = {0.f, 0.f, 0.f, 0.f};
  float pd[4] = {0.f, 0.f, 0.f, 0.f};
#pragma unroll
  for (int n = 0; n < 8; ++n) {
    float sa = asrc[n * 16 + r];
    float sd = adst[n * 16 + r];
#pragma unroll
    for (int rr = 0; rr < 4; ++rr) {
      float v = acc[n][rr];
      hb[(rowbase + g * 4 + rr) * 128 + n * 16 + r] = f2b(v);
      ps[rr] = fmaf(v, sa, ps[rr]);
      pd[rr] = fmaf(v, sd, pd[rr]);
    }
  }
#pragma unroll
  for (int rr = 0; rr < 4; ++rr) {
#pragma unroll
    for (int m = 1; m <= 8; m <<= 1) {
      ps[rr] += __shfl_xor(ps[rr], m, 64);
      pd[rr] += __shfl_xor(pd[rr], m, 64);
    }
  }
  if (r == 0) {
#pragma unroll
    for (int rr = 0; rr < 4; ++rr) {
      es[rowbase + g * 4 + rr] = ps[rr];
      ed[rowbase + g * 4 + rr] = pd[rr];
    }
  }
}

#define CEX(a, b, up)                         \
  do {                                        \
    if (((a) > (b)) == (up)) {                \
      unsigned long long _t = (a);            \
      (a) = (b);                              \
      (b) = _t;                               \
    }                                         \
  } while (0)

// ---------------------------------------------------------------------------
// Fully-fused attention tail. grid (NB, 4): block = one batch x 32-dim slice,
// 512 threads. Phases:
//  A: u64 bitonic sort of (tkey(s)|idx) in LDS (dup per dq slice).
//  B: hierarchical shfl scan of (e1,e2) -> sc[] (element-granular prefix).
//  C: per-chunk (8 src) weighted sums for the 32-dim slice -> s1/s2 LDS.
//  D: serial exclusive chunk prefix in LDS (+ totals row).
//  E: per-target: binsearch keys, coeffs, residual gather, write output.
// e1/e2 are recomputed from decoded keys everywhere -> bit-identical values.
// ---------------------------------------------------------------------------
template <bool APPLY_BN>
__global__ __launch_bounds__(512) void k_attn(
    const unsigned short* __restrict__ hb, const float* __restrict__ es,
    const float* __restrict__ ed, const float* __restrict__ bias,
    const float* __restrict__ bng, const float* __restrict__ bnb,
    const float* __restrict__ bnm, const float* __restrict__ bnv,
    float* __restrict__ xo, unsigned short* __restrict__ xbo) {
  __shared__ unsigned long long keys[NP];   // 8192 B
  __shared__ float2 sc[NN];                 // 8000 B
  __shared__ float s1[NC + 1][32];          // 16128 B
  __shared__ float s2[NC + 1][32];          // 16128 B
  __shared__ float2 wtot[8];
  int tid = threadIdx.x, b = blockIdx.x, dq = blockIdx.y;

  // ---- A: load + sort ----
  for (int i = tid; i < NP; i += 512) {
    unsigned long long kk;
    if (i < NN) {
      kk = ((unsigned long long)tkey(es[b * NN + i]) << 32) | (unsigned)i;
    } else {
      kk = (0xFF800000ull << 32) | (unsigned)i;  // tkey(+INF) pad
    }
    keys[i] = kk;
  }
  __syncthreads();
  int i0 = tid * 2;
  {
    unsigned long long q0 = keys[i0], q1 = keys[i0 + 1];
    CEX(q0, q1, (i0 & 2) == 0);
    keys[i0] = q0; keys[i0 + 1] = q1;
  }
  __syncthreads();
  for (int k = 4; k <= NP; k <<= 1) {
    for (int j = k >> 1; j >= 2; j >>= 1) {
      int i = ((tid & ~(j - 1)) << 1) | (tid & (j - 1));
      int ixj = i | j;
      bool up = ((i & k) == 0);
      unsigned long long a = keys[i], c = keys[ixj];
      if ((a > c) == up) { keys[i] = c; keys[ixj] = a; }
      __syncthreads();
    }
    {
      unsigned long long q0 = keys[i0], q1 = keys[i0 + 1];
      CEX(q0, q1, (i0 & k) == 0);
      keys[i0] = q0; keys[i0 + 1] = q1;
    }
    __syncthreads();
  }

  // ---- B: scan of (e1,e2) ----
  float2 f0 = make_float2(0.f, 0.f), f1 = make_float2(0.f, 0.f);
  {
    unsigned long long k0 = keys[i0], k1 = keys[i0 + 1];
    if (i0 < NN) {
      float s = tdec((unsigned)(k0 >> 32));
      f0.x = __expf(s);
      f0.y = __expf(0.2f * s);
    }
    if (i0 + 1 < NN) {
      float s = tdec((unsigned)(k1 >> 32));
      f1.x = __expf(s);
      f1.y = __expf(0.2f * s);
    }
  }
  int lane = tid & 63, wid = tid >> 6;
  float tx = f0.x + f1.x, ty = f0.y + f1.y;
  float ix = tx, iy = ty;
#pragma unroll
  for (int dlt = 1; dlt < 64; dlt <<= 1) {
    float ox = __shfl_up(ix, dlt, 64);
    float oy = __shfl_up(iy, dlt, 64);
    if (lane >= dlt) { ix += ox; iy += oy; }
  }
  if (lane == 63) wtot[wid] = make_float2(ix, iy);
  __syncthreads();
  float bx = 0.f, by = 0.f;
#pragma unroll
  for (int ww = 0; ww < 8; ++ww) {
    if (ww < wid) {
      float2 t = wtot[ww];
      bx += t.x;
      by += t.y;
    }
  }
  float exx = bx + ix - tx, eyy = by + iy - ty;  // exclusive at i0
  float in0x = exx + f0.x, in0y = eyy + f0.y;
  if (i0 < NN) sc[i0] = make_float2(in0x, in0y);
  if (i0 + 1 < NN) sc[i0 + 1] = make_float2(in0x + f1.x, in0y + f1.y);

  // ---- C: chunk sums for this 32-dim slice (keys stable; no sc dependency) ----
  int d = tid & 31;
  int cl = tid >> 5;  // 16 chunk lanes
  int dglob = dq * 32 + d;
  for (int c = cl; c < NC; c += 16) {
    float v1 = 0.f, v2 = 0.f;
#pragma unroll
    for (int u = 0; u < CS; ++u) {
      unsigned long long kk = keys[c * CS + u];
      int p = (int)(unsigned)kk;
      float s = tdec((unsigned)(kk >> 32));
      float e1 = __expf(s), e2 = __expf(0.2f * s);
      float hv = b2f(hb[((long)b * NN + p) * HD + dglob]);
      v1 = fmaf(e1, hv, v1);
      v2 = fmaf(e2, hv, v2);
    }
    s1[c][d] = v1;
    s2[c][d] = v2;
  }
  __syncthreads();

  // ---- D: serial exclusive chunk prefix (+ totals) ----
  if (tid < 32) {
    float r = 0.f;
    for (int c = 0; c < NC; ++c) {
      float v = s1[c][tid];
      s1[c][tid] = r;
      r += v;
    }
    s1[NC][tid] = r;
  } else if (tid < 64) {
    int dd = tid - 32;
    float r = 0.f;
    for (int c = 0; c < NC; ++c) {
      float v = s2[c][dd];
      s2[c][dd] = r;
      r += v;
    }
    s2[NC][dd] = r;
  }
  __syncthreads();

  // ---- E: per-target output ----
  float s1tot = sc[NN - 1].x;
  float T1 = s1[NC][d];
  float bs = bias[dglob];
  float bsc = 0.f, bsh = 0.f;
  if (APPLY_BN) {
    float g = bng[dglob], bb2 = bnb[dglob], m = bnm[dglob], v = bnv[dglob];
    bsc = g * rsqrtf(v + BN_EPS);
    bsh = bb2 - m * bsc;
  }
  int tq = tid >> 5;  // 16 target groups
  for (int i = tq; i < NN; i += 16) {
    float di = ed[b * NN + i];
    unsigned tt = tkey(-di);
    int lo = 0, hi = NP;
    while (lo < hi) {
      int mid = (lo + hi) >> 1;
      if ((unsigned)(keys[mid] >> 32) <= tt) lo = mid + 1; else hi = mid;
    }
    int k = lo;  // #{s_j <= t_i} <= NN
    float p1 = (k > 0) ? sc[k - 1].x : 0.f;
    float p2 = (k > 0) ? sc[k - 1].y : 0.f;
    float Ed = __expf(di);
    float Ed2 = __expf(0.2f * di);
    float den = fmaf(Ed, s1tot - p1, Ed2 * p2);
    float al = Ed / den, bt = Ed2 / den;
    int c = k >> 3;
    float base1 = s1[c][d];
    float base2 = s2[c][d];
    float r1 = 0.f, r2 = 0.f;
    for (int j = c * CS; j < k; ++j) {
      unsigned long long kk = keys[j];
      int p = (int)(unsigned)kk;
      float s = tdec((unsigned)(kk >> 32));
      float e1 = __expf(s), e2 = __expf(0.2f * s);
      float hv = b2f(hb[((long)b * NN + p) * HD + dglob]);
      r1 = fmaf(e1, hv, r1);
      r2 = fmaf(e2, hv, r2);
    }
    float val = fmaf(al, T1 - base1 - r1, fmaf(bt, base2 + r2, bs));
    long off = ((long)b * NN + i) * HD + dglob;
    if (APPLY_BN) {
      xbo[off] = f2b(fmaxf(fmaf(val, bsc, bsh), 0.f));
    } else {
      xo[off] = val;
    }
  }
}

extern "C" void kernel_launch(void* const* d_in, const int* in_sizes, int n_in,
                              void* d_out, int out_size, void* d_ws,
                              size_t ws_size, hipStream_t stream) {
  const float* locs = (const float*)d_in[0];
  const float* le_W0 = (const float*)d_in[1];
  const float* le_b0 = (const float*)d_in[2];
  const float* le_W1 = (const float*)d_in[3];
  const float* le_b1 = (const float*)d_in[4];
  const float* le_bn_g = (const float*)d_in[5];
  const float* le_bn_b = (const float*)d_in[6];
  const float* le_bn_m = (const float*)d_in[7];
  const float* le_bn_v = (const float*)d_in[8];
  const float* le_Wo = (const float*)d_in[9];
  const float* le_bo = (const float*)d_in[10];
  const float* gat_W = (const float*)d_in[11];
  const float* gat_asrc = (const float*)d_in[12];
  const float* gat_adst = (const float*)d_in[13];
  const float* gat_b = (const float*)d_in[14];
  const float* bn_g = (const float*)d_in[15];
  const float* bn_b = (const float*)d_in[16];
  const float* bn_m = (const float*)d_in[17];
  const float* bn_v = (const float*)d_in[18];

  float* out = (float*)d_out;                          // final f32 output
  unsigned short* hb = (unsigned short*)d_ws;          // 8,192,000 bf16
  float* es = (float*)(hb + 8192000);                  // 64,000 f32
  float* ed = es + 64000;
  unsigned short* xb = (unsigned short*)(ed + 64000);  // 8,192,000 bf16
  unsigned short* WT = xb + 8192000;                   // 49,152 bf16

  k_embed<<<1000, 256, 0, stream>>>(locs, le_W0, le_b0, le_W1, le_b1, le_bn_g,
                                    le_bn_b, le_bn_m, le_bn_v, le_Wo, le_bo,
                                    gat_W, WT, xb);
  for (int l = 0; l < 3; ++l) {
    k_gemm_e<<<1000, 256, 0, stream>>>(xb, WT + l * 16384,
                                       gat_asrc + l * 128, gat_adst + l * 128,
                                       hb, es, ed);
    if (l < 2) {
      k_attn<true><<<dim3(NB, 4), 512, 0, stream>>>(
          hb, es, ed, gat_b + l * 128, bn_g + l * 128, bn_b + l * 128,
          bn_m + l * 128, bn_v + l * 128, nullptr, xb);
    } else {
      k_attn<false><<<dim3(NB, 4), 512, 0, stream>>>(
          hb, es, ed, gat_b + 2 * 128, nullptr, nullptr, nullptr, nullptr,
          out, nullptr);
    }
  }
}

// Round 13
// 243.797 us; speedup vs baseline: 1.4907x; 1.4907x over previous
//
#include <hip/hip_runtime.h>
#include <hip/hip_bf16.h>

#define BN_EPS 1e-5f
#define NB 64
#define NN 1000
#define NP 1024
#define HD 128
#define CS 8
#define NC 125  // NN/CS exactly

typedef short bf16x8 __attribute__((ext_vector_type(8)));
typedef float f32x4 __attribute__((ext_vector_type(4)));

__device__ __forceinline__ unsigned short f2b(float f) {
  __hip_bfloat16 h = __float2bfloat16(f);
  return *reinterpret_cast<unsigned short*>(&h);
}
__device__ __forceinline__ float b2f(unsigned short u) {
  unsigned v = ((unsigned)u) << 16;
  return __uint_as_float(v);
}
// monotonic float -> uint (unsigned compare == float compare)
__device__ __forceinline__ unsigned tkey(float f) {
  unsigned u = __float_as_uint(f);
  return u ^ ((unsigned)((int)u >> 31) | 0x80000000u);
}

// ---------------------------------------------------------------------------
// Embedding MLP, register-tiled. 64 nodes/block. Writes xb (bf16).
// Blocks 0..191 also transpose the 3 GAT weights into WT (bf16).
// ---------------------------------------------------------------------------
__global__ __launch_bounds__(256) void k_embed(
    const float* __restrict__ locs,
    const float* __restrict__ W0, const float* __restrict__ b0,
    const float* __restrict__ W1, const float* __restrict__ b1,
    const float* __restrict__ g1, const float* __restrict__ be1,
    const float* __restrict__ m1, const float* __restrict__ v1,
    const float* __restrict__ Wo, const float* __restrict__ bo,
    const float* __restrict__ gatW, unsigned short* __restrict__ WT,
    unsigned short* __restrict__ xb) {
  __shared__ float z1T[64][68];
  __shared__ float z2T[64][68];
  int tid = threadIdx.x;
  long base = (long)blockIdx.x * 64;

  if (blockIdx.x < 192) {  // fused W transpose: 49152 elems
    int idx = blockIdx.x * 256 + tid;
    int lay = idx >> 14, rem = idx & 16383;
    int n = rem >> 7, kk = rem & 127;
    WT[idx] = f2b(gatW[lay * 16384 + kk * 128 + n]);
  }

  {
    int d = tid & 63;
    int q = tid >> 6;
    float w0x = W0[d], w0y = W0[64 + d], bb = b0[d];
#pragma unroll
    for (int g = 0; g < 4; ++g) {
      float vv[4];
#pragma unroll
      for (int i = 0; i < 4; ++i) {
        int n = g * 16 + q * 4 + i;
        float lx = locs[(base + n) * 2 + 0];
        float ly = locs[(base + n) * 2 + 1];
        vv[i] = fmaxf(fmaf(lx, w0x, fmaf(ly, w0y, bb)), 0.f);
      }
      *(float4*)&z1T[d][g * 16 + q * 4] = make_float4(vv[0], vv[1], vv[2], vv[3]);
    }
  }
  __syncthreads();

  int nt = tid & 15;
  int dt = tid >> 4;

  {
    float acc[4][4];
#pragma unroll
    for (int i = 0; i < 4; ++i)
#pragma unroll
      for (int j = 0; j < 4; ++j) acc[i][j] = 0.f;
#pragma unroll 4
    for (int k = 0; k < 64; ++k) {
      float4 zv = *(const float4*)&z1T[k][4 * nt];
      float4 wv = *(const float4*)&W1[k * 64 + 4 * dt];
      float zz[4] = {zv.x, zv.y, zv.z, zv.w};
      float ww[4] = {wv.x, wv.y, wv.z, wv.w};
#pragma unroll
      for (int i = 0; i < 4; ++i)
#pragma unroll
        for (int j = 0; j < 4; ++j) acc[i][j] = fmaf(zz[i], ww[j], acc[i][j]);
    }
    float4 b1v = *(const float4*)&b1[4 * dt];
    float4 g1v = *(const float4*)&g1[4 * dt];
    float4 bev = *(const float4*)&be1[4 * dt];
    float4 m1v = *(const float4*)&m1[4 * dt];
    float4 v1v = *(const float4*)&v1[4 * dt];
    float bbv[4] = {b1v.x, b1v.y, b1v.z, b1v.w};
    float ggv[4] = {g1v.x, g1v.y, g1v.z, g1v.w};
    float eev[4] = {bev.x, bev.y, bev.z, bev.w};
    float mmv[4] = {m1v.x, m1v.y, m1v.z, m1v.w};
    float vvv[4] = {v1v.x, v1v.y, v1v.z, v1v.w};
#pragma unroll
    for (int j = 0; j < 4; ++j) {
      float sc = ggv[j] * rsqrtf(vvv[j] + BN_EPS);
      float sh = eev[j] - mmv[j] * sc;
      float o[4];
#pragma unroll
      for (int i = 0; i < 4; ++i)
        o[i] = fmaxf(fmaf(acc[i][j] + bbv[j], sc, sh), 0.f);
      *(float4*)&z2T[4 * dt + j][4 * nt] = make_float4(o[0], o[1], o[2], o[3]);
    }
  }
  __syncthreads();

  {
    float acc[4][8];
#pragma unroll
    for (int i = 0; i < 4; ++i)
#pragma unroll
      for (int j = 0; j < 8; ++j) acc[i][j] = 0.f;
#pragma unroll 2
    for (int k = 0; k < 64; ++k) {
      float4 zv = *(const float4*)&z2T[k][4 * nt];
      float4 wa = *(const float4*)&Wo[k * 128 + 4 * dt];
      float4 wb = *(const float4*)&Wo[k * 128 + 64 + 4 * dt];
      float zz[4] = {zv.x, zv.y, zv.z, zv.w};
      float w0[4] = {wa.x, wa.y, wa.z, wa.w};
      float w1[4] = {wb.x, wb.y, wb.z, wb.w};
#pragma unroll
      for (int i = 0; i < 4; ++i) {
#pragma unroll
        for (int j = 0; j < 4; ++j) {
          acc[i][j] = fmaf(zz[i], w0[j], acc[i][j]);
          acc[i][4 + j] = fmaf(zz[i], w1[j], acc[i][4 + j]);
        }
      }
    }
    float4 bo0 = *(const float4*)&bo[4 * dt];
    float4 bo1 = *(const float4*)&bo[64 + 4 * dt];
    float bb0[4] = {bo0.x, bo0.y, bo0.z, bo0.w};
    float bb1[4] = {bo1.x, bo1.y, bo1.z, bo1.w};
#pragma unroll
    for (int i = 0; i < 4; ++i) {
      ushort4 p0, p1;
      p0.x = f2b(acc[i][0] + bb0[0]); p0.y = f2b(acc[i][1] + bb0[1]);
      p0.z = f2b(acc[i][2] + bb0[2]); p0.w = f2b(acc[i][3] + bb0[3]);
      p1.x = f2b(acc[i][4] + bb1[0]); p1.y = f2b(acc[i][5] + bb1[1]);
      p1.z = f2b(acc[i][6] + bb1[2]); p1.w = f2b(acc[i][7] + bb1[3]);
      *(ushort4*)&xb[(base + 4 * nt + i) * 128 + 4 * dt] = p0;
      *(ushort4*)&xb[(base + 4 * nt + i) * 128 + 64 + 4 * dt] = p1;
    }
  }
}

// ---------------------------------------------------------------------------
// h = xb @ W via MFMA 16x16x32 bf16. No LDS. Block = 4 waves, wave = 16 rows.
// Writes hb (bf16); e_src/e_dst dots from f32 accumulators.
// ---------------------------------------------------------------------------
__global__ __launch_bounds__(256) void k_gemm_e(
    const unsigned short* __restrict__ xb, const unsigned short* __restrict__ WT,
    const float* __restrict__ asrc, const float* __restrict__ adst,
    unsigned short* __restrict__ hb, float* __restrict__ es,
    float* __restrict__ ed) {
  int tid = threadIdx.x;
  int w = tid >> 6, l = tid & 63;
  long rowbase = (long)blockIdx.x * 64 + w * 16;
  int r = l & 15, g = l >> 4;

  f32x4 acc[8];
#pragma unroll
  for (int n = 0; n < 8; ++n) acc[n] = {0.f, 0.f, 0.f, 0.f};

#pragma unroll
  for (int ks = 0; ks < 4; ++ks) {
    bf16x8 a = *(const bf16x8*)&xb[(rowbase + r) * 128 + ks * 32 + g * 8];
#pragma unroll
    for (int n = 0; n < 8; ++n) {
      bf16x8 bfr = *(const bf16x8*)&WT[(n * 16 + r) * 128 + ks * 32 + g * 8];
      acc[n] = __builtin_amdgcn_mfma_f32_16x16x32_bf16(a, bfr, acc[n], 0, 0, 0);
    }
  }

  float ps[4] = {0.f, 0.f, 0.f, 0.f};
  float pd[4] = {0.f, 0.f, 0.f, 0.f};
#pragma unroll
  for (int n = 0; n < 8; ++n) {
    float sa = asrc[n * 16 + r];
    float sd = adst[n * 16 + r];
#pragma unroll
    for (int rr = 0; rr < 4; ++rr) {
      float v = acc[n][rr];
      hb[(rowbase + g * 4 + rr) * 128 + n * 16 + r] = f2b(v);
      ps[rr] = fmaf(v, sa, ps[rr]);
      pd[rr] = fmaf(v, sd, pd[rr]);
    }
  }
#pragma unroll
  for (int rr = 0; rr < 4; ++rr) {
#pragma unroll
    for (int m = 1; m <= 8; m <<= 1) {
      ps[rr] += __shfl_xor(ps[rr], m, 64);
      pd[rr] += __shfl_xor(pd[rr], m, 64);
    }
  }
  if (r == 0) {
#pragma unroll
    for (int rr = 0; rr < 4; ++rr) {
      es[rowbase + g * 4 + rr] = ps[rr];
      ed[rowbase + g * 4 + rr] = pd[rr];
    }
  }
}

#define CEX(a, b, up)                         \
  do {                                        \
    if (((a) > (b)) == (up)) {                \
      unsigned long long _t = (a);            \
      (a) = (b);                              \
      (b) = _t;                               \
    }                                         \
  } while (0)

// ---------------------------------------------------------------------------
// Per batch, 512 threads: u64-packed bitonic sort (2 elems/thread; j=1 pass in
// registers, LDS passes are single-iteration), hierarchical shfl scan of
// (e1,e2), per-target binsearch coefficients.
// ---------------------------------------------------------------------------
__global__ __launch_bounds__(512) void k_sort(
    const float* __restrict__ es, const float* __restrict__ ed,
    float* __restrict__ e1s, float* __restrict__ e2s, int* __restrict__ perm,
    int* __restrict__ kcut, float* __restrict__ alpha,
    float* __restrict__ beta) {
  __shared__ unsigned long long keys[NP];
  __shared__ float2 sc[NP];
  __shared__ float2 wtot[8];
  int tid = threadIdx.x, b = blockIdx.x;
  for (int i = tid; i < NP; i += 512) {
    unsigned long long kk;
    if (i < NN) {
      kk = ((unsigned long long)tkey(es[b * NN + i]) << 32) | (unsigned)i;
    } else {
      kk = (0xFF800000ull << 32) | (unsigned)i;  // +INF pad
    }
    keys[i] = kk;
  }
  __syncthreads();
  int i0 = tid * 2;
  // k=2 stage (j=1), local
  {
    unsigned long long q0 = keys[i0], q1 = keys[i0 + 1];
    CEX(q0, q1, (i0 & 2) == 0);
    keys[i0] = q0; keys[i0 + 1] = q1;
  }
  __syncthreads();
  for (int k = 4; k <= NP; k <<= 1) {
    for (int j = k >> 1; j >= 2; j >>= 1) {
      int i = ((tid & ~(j - 1)) << 1) | (tid & (j - 1));
      int ixj = i | j;
      bool up = ((i & k) == 0);
      unsigned long long a = keys[i], c = keys[ixj];
      if ((a > c) == up) { keys[i] = c; keys[ixj] = a; }
      __syncthreads();
    }
    {
      unsigned long long q0 = keys[i0], q1 = keys[i0 + 1];
      CEX(q0, q1, (i0 & k) == 0);
      keys[i0] = q0; keys[i0 + 1] = q1;
    }
    __syncthreads();
  }
  // extract sorted s -> e1/e2/perm; thread-local pair for scan
  float2 f0 = make_float2(0.f, 0.f), f1 = make_float2(0.f, 0.f);
  {
    unsigned long long k0 = keys[i0], k1 = keys[i0 + 1];
    if (i0 < NN) {
      unsigned m = (unsigned)(k0 >> 32);
      unsigned u = (m & 0x80000000u) ? (m ^ 0x80000000u) : ~m;
      float s = __uint_as_float(u);
      f0.x = __expf(s);
      f0.y = __expf(0.2f * s);
      e1s[b * NN + i0] = f0.x;
      e2s[b * NN + i0] = f0.y;
      perm[b * NN + i0] = (int)(unsigned)k0;
    }
    if (i0 + 1 < NN) {
      unsigned m = (unsigned)(k1 >> 32);
      unsigned u = (m & 0x80000000u) ? (m ^ 0x80000000u) : ~m;
      float s = __uint_as_float(u);
      f1.x = __expf(s);
      f1.y = __expf(0.2f * s);
      e1s[b * NN + i0 + 1] = f1.x;
      e2s[b * NN + i0 + 1] = f1.y;
      perm[b * NN + i0 + 1] = (int)(unsigned)k1;
    }
  }
  // hierarchical inclusive scan of (e1,e2)
  int lane = tid & 63, wid = tid >> 6;
  float tx = f0.x + f1.x, ty = f0.y + f1.y;
  float ix = tx, iy = ty;
#pragma unroll
  for (int dlt = 1; dlt < 64; dlt <<= 1) {
    float ox = __shfl_up(ix, dlt, 64);
    float oy = __shfl_up(iy, dlt, 64);
    if (lane >= dlt) { ix += ox; iy += oy; }
  }
  if (lane == 63) wtot[wid] = make_float2(ix, iy);
  __syncthreads();
  float bx = 0.f, by = 0.f;
#pragma unroll
  for (int ww = 0; ww < 8; ++ww) {
    if (ww < wid) {
      float2 t = wtot[ww];
      bx += t.x;
      by += t.y;
    }
  }
  float ex = bx + ix - tx, ey = by + iy - ty;  // exclusive at i0
  float in0x = ex + f0.x, in0y = ey + f0.y;
  sc[i0] = make_float2(in0x, in0y);
  sc[i0 + 1] = make_float2(in0x + f1.x, in0y + f1.y);
  __syncthreads();
  float s1tot = sc[NN - 1].x;
  // per-target coefficients (2 iters)
  for (int i = tid; i < NN; i += 512) {
    float di = ed[b * NN + i];
    unsigned tt = tkey(-di);
    int lo = 0, hi = NP;
    while (lo < hi) {
      int mid = (lo + hi) >> 1;
      if ((unsigned)(keys[mid] >> 32) <= tt) lo = mid + 1; else hi = mid;
    }
    int k = lo;  // #{s_j <= t_i} <= NN (pads are +INF)
    float p1 = (k > 0) ? sc[k - 1].x : 0.f;
    float p2 = (k > 0) ? sc[k - 1].y : 0.f;
    float Ed = __expf(di);
    float Ed2 = __expf(0.2f * di);
    float den = fmaf(Ed, s1tot - p1, Ed2 * p2);
    kcut[b * NN + i] = k;
    alpha[b * NN + i] = Ed / den;
    beta[b * NN + i] = Ed2 / den;
  }
}

// ---------------------------------------------------------------------------
// Fused chunk-sums + exclusive chunk-prefix. grid (NB, 4): block owns a 32-dim
// slice of one batch (32.25 KB LDS -> 4+ blocks/CU). Phase 1: 8 chunk-lanes x
// 32 dims gather per-chunk weighted sums into LDS. Phase 2: serial prefix.
// Phase 3: coalesced store of exclusive prefix + totals.
// ---------------------------------------------------------------------------
__global__ __launch_bounds__(256) void k_cpfx(
    const unsigned short* __restrict__ hb, const float* __restrict__ e1s,
    const float* __restrict__ e2s, const int* __restrict__ perm,
    float* __restrict__ C1, float* __restrict__ C2) {
  __shared__ float s1[NC + 1][32];
  __shared__ float s2[NC + 1][32];
  int tid = threadIdx.x, b = blockIdx.x, dq = blockIdx.y;
  int d = tid & 31;
  int cl = tid >> 5;  // chunk lane 0..7
  int dglob = dq * 32 + d;
  for (int c = cl; c < NC; c += 8) {
    float v1 = 0.f, v2 = 0.f;
#pragma unroll
    for (int u = 0; u < CS; ++u) {
      int j = c * CS + u;
      int p = perm[b * NN + j];
      float hv = b2f(hb[((long)b * NN + p) * HD + dglob]);
      v1 = fmaf(e1s[b * NN + j], hv, v1);
      v2 = fmaf(e2s[b * NN + j], hv, v2);
    }
    s1[c][d] = v1;
    s2[c][d] = v2;
  }
  __syncthreads();
  if (tid < 32) {
    float r = 0.f;
    for (int c = 0; c < NC; ++c) {
      float v = s1[c][tid];
      s1[c][tid] = r;
      r += v;
    }
    s1[NC][tid] = r;
  } else if (tid < 64) {
    int dd = tid - 32;
    float r = 0.f;
    for (int c = 0; c < NC; ++c) {
      float v = s2[c][dd];
      s2[c][dd] = r;
      r += v;
    }
    s2[NC][dd] = r;
  }
  __syncthreads();
  long base = (long)b * (NC + 1) * HD + dq * 32;
  for (int i = tid; i < (NC + 1) * 32; i += 256) {
    int c = i >> 5, dd = i & 31;
    C1[base + (long)c * HD + dd] = s1[c][dd];
    C2[base + (long)c * HD + dd] = s2[c][dd];
  }
}

// ---------------------------------------------------------------------------
// out[i] = alpha_i*(T1 - C1[c_i] - partial1) + beta_i*(C2[c_i] + partial2)
// APPLY_BN=true: writes bf16 xb (intermediate); false: writes f32 out.
// ---------------------------------------------------------------------------
template <bool APPLY_BN>
__global__ __launch_bounds__(128) void k_out(
    const unsigned short* __restrict__ hb, const float* __restrict__ C1,
    const float* __restrict__ C2, const float* __restrict__ e1s,
    const float* __restrict__ e2s, const int* __restrict__ perm,
    const int* __restrict__ kcut, const float* __restrict__ alpha,
    const float* __restrict__ beta, const float* __restrict__ bias,
    const float* __restrict__ bng, const float* __restrict__ bnb,
    const float* __restrict__ bnm, const float* __restrict__ bnv,
    float* __restrict__ xo, unsigned short* __restrict__ xbo) {
  int d = threadIdx.x, b = blockIdx.x;
  int i0 = blockIdx.y * 8;
  float T1 = C1[((long)b * (NC + 1) + NC) * HD + d];
  float bs = bias[d];
  float sc = 0.f, sh = 0.f;
  if (APPLY_BN) {
    float g = bng[d], bb = bnb[d], m = bnm[d], v = bnv[d];
    sc = g * rsqrtf(v + BN_EPS);
    sh = bb - m * sc;
  }
  for (int i = i0; i < i0 + 8; ++i) {
    int k = kcut[b * NN + i];
    float al = alpha[b * NN + i], bt = beta[b * NN + i];
    int c = k >> 3;
    float base1 = C1[((long)b * (NC + 1) + c) * HD + d];
    float base2 = C2[((long)b * (NC + 1) + c) * HD + d];
    float p1 = 0.f, p2 = 0.f;
    for (int j = c * CS; j < k; ++j) {
      int p = perm[b * NN + j];
      float hv = b2f(hb[((long)b * NN + p) * HD + d]);
      p1 = fmaf(e1s[b * NN + j], hv, p1);
      p2 = fmaf(e2s[b * NN + j], hv, p2);
    }
    float val = fmaf(al, T1 - base1 - p1, fmaf(bt, base2 + p2, bs));
    long off = ((long)b * NN + i) * HD + d;
    if (APPLY_BN) {
      xbo[off] = f2b(fmaxf(fmaf(val, sc, sh), 0.f));
    } else {
      xo[off] = val;
    }
  }
}

extern "C" void kernel_launch(void* const* d_in, const int* in_sizes, int n_in,
                              void* d_out, int out_size, void* d_ws,
                              size_t ws_size, hipStream_t stream) {
  const float* locs = (const float*)d_in[0];
  const float* le_W0 = (const float*)d_in[1];
  const float* le_b0 = (const float*)d_in[2];
  const float* le_W1 = (const float*)d_in[3];
  const float* le_b1 = (const float*)d_in[4];
  const float* le_bn_g = (const float*)d_in[5];
  const float* le_bn_b = (const float*)d_in[6];
  const float* le_bn_m = (const float*)d_in[7];
  const float* le_bn_v = (const float*)d_in[8];
  const float* le_Wo = (const float*)d_in[9];
  const float* le_bo = (const float*)d_in[10];
  const float* gat_W = (const float*)d_in[11];
  const float* gat_asrc = (const float*)d_in[12];
  const float* gat_adst = (const float*)d_in[13];
  const float* gat_b = (const float*)d_in[14];
  const float* bn_g = (const float*)d_in[15];
  const float* bn_b = (const float*)d_in[16];
  const float* bn_m = (const float*)d_in[17];
  const float* bn_v = (const float*)d_in[18];

  float* out = (float*)d_out;                          // final f32 output
  unsigned short* hb = (unsigned short*)d_ws;          // 8,192,000 bf16
  float* C1 = (float*)(hb + 8192000);                  // 1,032,192 f32
  float* C2 = C1 + 1032192;                            // 1,032,192
  float* es = C2 + 1032192;
  float* ed = es + 64000;
  float* e1s = ed + 64000;
  float* e2s = e1s + 64000;
  float* alpha = e2s + 64000;
  float* beta = alpha + 64000;
  int* perm = (int*)(beta + 64000);
  int* kcut = perm + 64000;
  unsigned short* xb = (unsigned short*)(kcut + 64000);  // 8,192,000 bf16
  unsigned short* WT = xb + 8192000;                      // 49,152 bf16

  k_embed<<<1000, 256, 0, stream>>>(locs, le_W0, le_b0, le_W1, le_b1, le_bn_g,
                                    le_bn_b, le_bn_m, le_bn_v, le_Wo, le_bo,
                                    gat_W, WT, xb);
  for (int l = 0; l < 3; ++l) {
    k_gemm_e<<<1000, 256, 0, stream>>>(xb, WT + l * 16384,
                                       gat_asrc + l * 128, gat_adst + l * 128,
                                       hb, es, ed);
    k_sort<<<NB, 512, 0, stream>>>(es, ed, e1s, e2s, perm, kcut, alpha, beta);
    k_cpfx<<<dim3(NB, 4), 256, 0, stream>>>(hb, e1s, e2s, perm, C1, C2);
    if (l < 2) {
      k_out<true><<<dim3(NB, NC), 128, 0, stream>>>(
          hb, C1, C2, e1s, e2s, perm, kcut, alpha, beta, gat_b + l * 128,
          bn_g + l * 128, bn_b + l * 128, bn_m + l * 128, bn_v + l * 128,
          nullptr, xb);
    } else {
      k_out<false><<<dim3(NB, NC), 128, 0, stream>>>(
          hb, C1, C2, e1s, e2s, perm, kcut, alpha, beta, gat_b + 2 * 128,
          nullptr, nullptr, nullptr, nullptr, out, nullptr);
    }
  }
}

// Round 14
// 236.187 us; speedup vs baseline: 1.5387x; 1.0322x over previous
//
#include <hip/hip_runtime.h>
#include <hip/hip_bf16.h>

#define BN_EPS 1e-5f
#define NB 64
#define NN 1000
#define NP 1024
#define HD 128
#define CS 8
#define NC 125  // NN/CS exactly

typedef short bf16x8 __attribute__((ext_vector_type(8)));
typedef float f32x4 __attribute__((ext_vector_type(4)));

__device__ __forceinline__ unsigned short f2b(float f) {
  __hip_bfloat16 h = __float2bfloat16(f);
  return *reinterpret_cast<unsigned short*>(&h);
}
__device__ __forceinline__ float b2f(unsigned short u) {
  unsigned v = ((unsigned)u) << 16;
  return __uint_as_float(v);
}
// monotonic float -> uint (unsigned compare == float compare)
__device__ __forceinline__ unsigned tkey(float f) {
  unsigned u = __float_as_uint(f);
  return u ^ ((unsigned)((int)u >> 31) | 0x80000000u);
}

// ---------------------------------------------------------------------------
// Embedding MLP, register-tiled. 64 nodes/block. Writes xb (bf16).
// Blocks 0..191 also transpose the 3 GAT weights into WT (bf16).
// ---------------------------------------------------------------------------
__global__ __launch_bounds__(256) void k_embed(
    const float* __restrict__ locs,
    const float* __restrict__ W0, const float* __restrict__ b0,
    const float* __restrict__ W1, const float* __restrict__ b1,
    const float* __restrict__ g1, const float* __restrict__ be1,
    const float* __restrict__ m1, const float* __restrict__ v1,
    const float* __restrict__ Wo, const float* __restrict__ bo,
    const float* __restrict__ gatW, unsigned short* __restrict__ WT,
    unsigned short* __restrict__ xb) {
  __shared__ float z1T[64][68];
  __shared__ float z2T[64][68];
  int tid = threadIdx.x;
  long base = (long)blockIdx.x * 64;

  if (blockIdx.x < 192) {  // fused W transpose: 49152 elems
    int idx = blockIdx.x * 256 + tid;
    int lay = idx >> 14, rem = idx & 16383;
    int n = rem >> 7, kk = rem & 127;
    WT[idx] = f2b(gatW[lay * 16384 + kk * 128 + n]);
  }

  {
    int d = tid & 63;
    int q = tid >> 6;
    float w0x = W0[d], w0y = W0[64 + d], bb = b0[d];
#pragma unroll
    for (int g = 0; g < 4; ++g) {
      float vv[4];
#pragma unroll
      for (int i = 0; i < 4; ++i) {
        int n = g * 16 + q * 4 + i;
        float lx = locs[(base + n) * 2 + 0];
        float ly = locs[(base + n) * 2 + 1];
        vv[i] = fmaxf(fmaf(lx, w0x, fmaf(ly, w0y, bb)), 0.f);
      }
      *(float4*)&z1T[d][g * 16 + q * 4] = make_float4(vv[0], vv[1], vv[2], vv[3]);
    }
  }
  __syncthreads();

  int nt = tid & 15;
  int dt = tid >> 4;

  {
    float acc[4][4];
#pragma unroll
    for (int i = 0; i < 4; ++i)
#pragma unroll
      for (int j = 0; j < 4; ++j) acc[i][j] = 0.f;
#pragma unroll 4
    for (int k = 0; k < 64; ++k) {
      float4 zv = *(const float4*)&z1T[k][4 * nt];
      float4 wv = *(const float4*)&W1[k * 64 + 4 * dt];
      float zz[4] = {zv.x, zv.y, zv.z, zv.w};
      float ww[4] = {wv.x, wv.y, wv.z, wv.w};
#pragma unroll
      for (int i = 0; i < 4; ++i)
#pragma unroll
        for (int j = 0; j < 4; ++j) acc[i][j] = fmaf(zz[i], ww[j], acc[i][j]);
    }
    float4 b1v = *(const float4*)&b1[4 * dt];
    float4 g1v = *(const float4*)&g1[4 * dt];
    float4 bev = *(const float4*)&be1[4 * dt];
    float4 m1v = *(const float4*)&m1[4 * dt];
    float4 v1v = *(const float4*)&v1[4 * dt];
    float bbv[4] = {b1v.x, b1v.y, b1v.z, b1v.w};
    float ggv[4] = {g1v.x, g1v.y, g1v.z, g1v.w};
    float eev[4] = {bev.x, bev.y, bev.z, bev.w};
    float mmv[4] = {m1v.x, m1v.y, m1v.z, m1v.w};
    float vvv[4] = {v1v.x, v1v.y, v1v.z, v1v.w};
#pragma unroll
    for (int j = 0; j < 4; ++j) {
      float sc = ggv[j] * rsqrtf(vvv[j] + BN_EPS);
      float sh = eev[j] - mmv[j] * sc;
      float o[4];
#pragma unroll
      for (int i = 0; i < 4; ++i)
        o[i] = fmaxf(fmaf(acc[i][j] + bbv[j], sc, sh), 0.f);
      *(float4*)&z2T[4 * dt + j][4 * nt] = make_float4(o[0], o[1], o[2], o[3]);
    }
  }
  __syncthreads();

  {
    float acc[4][8];
#pragma unroll
    for (int i = 0; i < 4; ++i)
#pragma unroll
      for (int j = 0; j < 8; ++j) acc[i][j] = 0.f;
#pragma unroll 2
    for (int k = 0; k < 64; ++k) {
      float4 zv = *(const float4*)&z2T[k][4 * nt];
      float4 wa = *(const float4*)&Wo[k * 128 + 4 * dt];
      float4 wb = *(const float4*)&Wo[k * 128 + 64 + 4 * dt];
      float zz[4] = {zv.x, zv.y, zv.z, zv.w};
      float w0[4] = {wa.x, wa.y, wa.z, wa.w};
      float w1[4] = {wb.x, wb.y, wb.z, wb.w};
#pragma unroll
      for (int i = 0; i < 4; ++i) {
#pragma unroll
        for (int j = 0; j < 4; ++j) {
          acc[i][j] = fmaf(zz[i], w0[j], acc[i][j]);
          acc[i][4 + j] = fmaf(zz[i], w1[j], acc[i][4 + j]);
        }
      }
    }
    float4 bo0 = *(const float4*)&bo[4 * dt];
    float4 bo1 = *(const float4*)&bo[64 + 4 * dt];
    float bb0[4] = {bo0.x, bo0.y, bo0.z, bo0.w};
    float bb1[4] = {bo1.x, bo1.y, bo1.z, bo1.w};
#pragma unroll
    for (int i = 0; i < 4; ++i) {
      ushort4 p0, p1;
      p0.x = f2b(acc[i][0] + bb0[0]); p0.y = f2b(acc[i][1] + bb0[1]);
      p0.z = f2b(acc[i][2] + bb0[2]); p0.w = f2b(acc[i][3] + bb0[3]);
      p1.x = f2b(acc[i][4] + bb1[0]); p1.y = f2b(acc[i][5] + bb1[1]);
      p1.z = f2b(acc[i][6] + bb1[2]); p1.w = f2b(acc[i][7] + bb1[3]);
      *(ushort4*)&xb[(base + 4 * nt + i) * 128 + 4 * dt] = p0;
      *(ushort4*)&xb[(base + 4 * nt + i) * 128 + 64 + 4 * dt] = p1;
    }
  }
}

// ---------------------------------------------------------------------------
// h = xb @ W via MFMA 16x16x32 bf16. No LDS. Block = 4 waves, wave = 16 rows.
// Writes hb (bf16); e_src/e_dst dots from f32 accumulators.
// ---------------------------------------------------------------------------
__global__ __launch_bounds__(256) void k_gemm_e(
    const unsigned short* __restrict__ xb, const unsigned short* __restrict__ WT,
    const float* __restrict__ asrc, const float* __restrict__ adst,
    unsigned short* __restrict__ hb, float* __restrict__ es,
    float* __restrict__ ed) {
  int tid = threadIdx.x;
  int w = tid >> 6, l = tid & 63;
  long rowbase = (long)blockIdx.x * 64 + w * 16;
  int r = l & 15, g = l >> 4;

  f32x4 acc[8];
#pragma unroll
  for (int n = 0; n < 8; ++n) acc[n] = {0.f, 0.f, 0.f, 0.f};

#pragma unroll
  for (int ks = 0; ks < 4; ++ks) {
    bf16x8 a = *(const bf16x8*)&xb[(rowbase + r) * 128 + ks * 32 + g * 8];
#pragma unroll
    for (int n = 0; n < 8; ++n) {
      bf16x8 bfr = *(const bf16x8*)&WT[(n * 16 + r) * 128 + ks * 32 + g * 8];
      acc[n] = __builtin_amdgcn_mfma_f32_16x16x32_bf16(a, bfr, acc[n], 0, 0, 0);
    }
  }

  float ps[4] = {0.f, 0.f, 0.f, 0.f};
  float pd[4] = {0.f, 0.f, 0.f, 0.f};
#pragma unroll
  for (int n = 0; n < 8; ++n) {
    float sa = asrc[n * 16 + r];
    float sd = adst[n * 16 + r];
#pragma unroll
    for (int rr = 0; rr < 4; ++rr) {
      float v = acc[n][rr];
      hb[(rowbase + g * 4 + rr) * 128 + n * 16 + r] = f2b(v);
      ps[rr] = fmaf(v, sa, ps[rr]);
      pd[rr] = fmaf(v, sd, pd[rr]);
    }
  }
#pragma unroll
  for (int rr = 0; rr < 4; ++rr) {
#pragma unroll
    for (int m = 1; m <= 8; m <<= 1) {
      ps[rr] += __shfl_xor(ps[rr], m, 64);
      pd[rr] += __shfl_xor(pd[rr], m, 64);
    }
  }
  if (r == 0) {
#pragma unroll
    for (int rr = 0; rr < 4; ++rr) {
      es[rowbase + g * 4 + rr] = ps[rr];
      ed[rowbase + g * 4 + rr] = pd[rr];
    }
  }
}

#define CEX(a, b, up)                         \
  do {                                        \
    if (((a) > (b)) == (up)) {                \
      unsigned long long _t = (a);            \
      (a) = (b);                              \
      (b) = _t;                               \
    }                                         \
  } while (0)

// ---------------------------------------------------------------------------
// Per batch, 512 threads: u64-packed bitonic sort, hierarchical shfl scan of
// (e1,e2) -> e12 packed; per-target binsearch -> kcut + packed (alpha,beta).
// ---------------------------------------------------------------------------
__global__ __launch_bounds__(512) void k_sort(
    const float* __restrict__ es, const float* __restrict__ ed,
    float2* __restrict__ e12, int* __restrict__ perm, int* __restrict__ kcut,
    float2* __restrict__ ab) {
  __shared__ unsigned long long keys[NP];
  __shared__ float2 sc[NP];
  __shared__ float2 wtot[8];
  int tid = threadIdx.x, b = blockIdx.x;
  for (int i = tid; i < NP; i += 512) {
    unsigned long long kk;
    if (i < NN) {
      kk = ((unsigned long long)tkey(es[b * NN + i]) << 32) | (unsigned)i;
    } else {
      kk = (0xFF800000ull << 32) | (unsigned)i;  // +INF pad
    }
    keys[i] = kk;
  }
  __syncthreads();
  int i0 = tid * 2;
  {
    unsigned long long q0 = keys[i0], q1 = keys[i0 + 1];
    CEX(q0, q1, (i0 & 2) == 0);
    keys[i0] = q0; keys[i0 + 1] = q1;
  }
  __syncthreads();
  for (int k = 4; k <= NP; k <<= 1) {
    for (int j = k >> 1; j >= 2; j >>= 1) {
      int i = ((tid & ~(j - 1)) << 1) | (tid & (j - 1));
      int ixj = i | j;
      bool up = ((i & k) == 0);
      unsigned long long a = keys[i], c = keys[ixj];
      if ((a > c) == up) { keys[i] = c; keys[ixj] = a; }
      __syncthreads();
    }
    {
      unsigned long long q0 = keys[i0], q1 = keys[i0 + 1];
      CEX(q0, q1, (i0 & k) == 0);
      keys[i0] = q0; keys[i0 + 1] = q1;
    }
    __syncthreads();
  }
  // extract sorted s -> e12/perm; thread-local pair for scan
  float2 f0 = make_float2(0.f, 0.f), f1 = make_float2(0.f, 0.f);
  {
    unsigned long long k0 = keys[i0], k1 = keys[i0 + 1];
    if (i0 < NN) {
      unsigned m = (unsigned)(k0 >> 32);
      unsigned u = (m & 0x80000000u) ? (m ^ 0x80000000u) : ~m;
      float s = __uint_as_float(u);
      f0.x = __expf(s);
      f0.y = __expf(0.2f * s);
      e12[b * NN + i0] = f0;
      perm[b * NN + i0] = (int)(unsigned)k0;
    }
    if (i0 + 1 < NN) {
      unsigned m = (unsigned)(k1 >> 32);
      unsigned u = (m & 0x80000000u) ? (m ^ 0x80000000u) : ~m;
      float s = __uint_as_float(u);
      f1.x = __expf(s);
      f1.y = __expf(0.2f * s);
      e12[b * NN + i0 + 1] = f1;
      perm[b * NN + i0 + 1] = (int)(unsigned)k1;
    }
  }
  // hierarchical inclusive scan of (e1,e2)
  int lane = tid & 63, wid = tid >> 6;
  float tx = f0.x + f1.x, ty = f0.y + f1.y;
  float ix = tx, iy = ty;
#pragma unroll
  for (int dlt = 1; dlt < 64; dlt <<= 1) {
    float ox = __shfl_up(ix, dlt, 64);
    float oy = __shfl_up(iy, dlt, 64);
    if (lane >= dlt) { ix += ox; iy += oy; }
  }
  if (lane == 63) wtot[wid] = make_float2(ix, iy);
  __syncthreads();
  float bx = 0.f, by = 0.f;
#pragma unroll
  for (int ww = 0; ww < 8; ++ww) {
    if (ww < wid) {
      float2 t = wtot[ww];
      bx += t.x;
      by += t.y;
    }
  }
  float ex = bx + ix - tx, ey = by + iy - ty;  // exclusive at i0
  float in0x = ex + f0.x, in0y = ey + f0.y;
  sc[i0] = make_float2(in0x, in0y);
  sc[i0 + 1] = make_float2(in0x + f1.x, in0y + f1.y);
  __syncthreads();
  float s1tot = sc[NN - 1].x;
  // per-target coefficients (2 iters)
  for (int i = tid; i < NN; i += 512) {
    float di = ed[b * NN + i];
    unsigned tt = tkey(-di);
    int lo = 0, hi = NP;
    while (lo < hi) {
      int mid = (lo + hi) >> 1;
      if ((unsigned)(keys[mid] >> 32) <= tt) lo = mid + 1; else hi = mid;
    }
    int k = lo;  // #{s_j <= t_i} <= NN (pads are +INF)
    float p1 = (k > 0) ? sc[k - 1].x : 0.f;
    float p2 = (k > 0) ? sc[k - 1].y : 0.f;
    float Ed = __expf(di);
    float Ed2 = __expf(0.2f * di);
    float den = fmaf(Ed, s1tot - p1, Ed2 * p2);
    kcut[b * NN + i] = k;
    ab[b * NN + i] = make_float2(Ed / den, Ed2 / den);
  }
}

// ---------------------------------------------------------------------------
// Fused chunk-sums + exclusive chunk-prefix + sorted-h emission.
// grid (NB, 4): block = batch x 32-dim slice (32.25 KB LDS, 4+ blocks/CU).
// Phase 1: 8 chunk-lanes x 32 dims gather hb[perm[j]] -> chunk sums in LDS,
//          and write the gathered rows to hs[j] (sorted-order h copy).
// Phase 2: serial exclusive prefix. Phase 3: coalesced C store.
// ---------------------------------------------------------------------------
__global__ __launch_bounds__(256) void k_cpfx(
    const unsigned short* __restrict__ hb, const float2* __restrict__ e12,
    const int* __restrict__ perm, float* __restrict__ C1,
    float* __restrict__ C2, unsigned short* __restrict__ hs) {
  __shared__ float s1[NC + 1][32];
  __shared__ float s2[NC + 1][32];
  int tid = threadIdx.x, b = blockIdx.x, dq = blockIdx.y;
  int d = tid & 31;
  int cl = tid >> 5;  // chunk lane 0..7
  int dglob = dq * 32 + d;
  for (int c = cl; c < NC; c += 8) {
    float v1 = 0.f, v2 = 0.f;
#pragma unroll
    for (int u = 0; u < CS; ++u) {
      int j = c * CS + u;
      int p = perm[b * NN + j];
      unsigned short hraw = hb[((long)b * NN + p) * HD + dglob];
      hs[((long)b * NN + j) * HD + dglob] = hraw;
      float hv = b2f(hraw);
      float2 e = e12[b * NN + j];
      v1 = fmaf(e.x, hv, v1);
      v2 = fmaf(e.y, hv, v2);
    }
    s1[c][d] = v1;
    s2[c][d] = v2;
  }
  __syncthreads();
  if (tid < 32) {
    float r = 0.f;
    for (int c = 0; c < NC; ++c) {
      float v = s1[c][tid];
      s1[c][tid] = r;
      r += v;
    }
    s1[NC][tid] = r;
  } else if (tid < 64) {
    int dd = tid - 32;
    float r = 0.f;
    for (int c = 0; c < NC; ++c) {
      float v = s2[c][dd];
      s2[c][dd] = r;
      r += v;
    }
    s2[NC][dd] = r;
  }
  __syncthreads();
  long base = (long)b * (NC + 1) * HD + dq * 32;
  for (int i = tid; i < (NC + 1) * 32; i += 256) {
    int c = i >> 5, dd = i & 31;
    C1[base + (long)c * HD + dd] = s1[c][dd];
    C2[base + (long)c * HD + dd] = s2[c][dd];
  }
}

// ---------------------------------------------------------------------------
// out[i] = a_i*(T1 - C1[c_i] - res1) + b_i*(C2[c_i] + res2) + bias.
// Residual reads hs (sorted-order, consecutive rows, no indirection).
// APPLY_BN=true: writes bf16 xb (intermediate); false: writes f32 out.
// ---------------------------------------------------------------------------
template <bool APPLY_BN>
__global__ __launch_bounds__(128) void k_out(
    const unsigned short* __restrict__ hs, const float* __restrict__ C1,
    const float* __restrict__ C2, const float2* __restrict__ e12,
    const int* __restrict__ kcut, const float2* __restrict__ ab,
    const float* __restrict__ bias, const float* __restrict__ bng,
    const float* __restrict__ bnb, const float* __restrict__ bnm,
    const float* __restrict__ bnv, float* __restrict__ xo,
    unsigned short* __restrict__ xbo) {
  int d = threadIdx.x, b = blockIdx.x;
  int i0 = blockIdx.y * 8;
  float T1 = C1[((long)b * (NC + 1) + NC) * HD + d];
  float bs = bias[d];
  float sc = 0.f, sh = 0.f;
  if (APPLY_BN) {
    float g = bng[d], bb = bnb[d], m = bnm[d], v = bnv[d];
    sc = g * rsqrtf(v + BN_EPS);
    sh = bb - m * sc;
  }
  for (int i = i0; i < i0 + 8; ++i) {
    int k = kcut[b * NN + i];
    float2 coeff = ab[b * NN + i];
    int c = k >> 3;
    float base1 = C1[((long)b * (NC + 1) + c) * HD + d];
    float base2 = C2[((long)b * (NC + 1) + c) * HD + d];
    float p1 = 0.f, p2 = 0.f;
    for (int j = c * CS; j < k; ++j) {
      float hv = b2f(hs[((long)b * NN + j) * HD + d]);
      float2 e = e12[b * NN + j];
      p1 = fmaf(e.x, hv, p1);
      p2 = fmaf(e.y, hv, p2);
    }
    float val = fmaf(coeff.x, T1 - base1 - p1, fmaf(coeff.y, base2 + p2, bs));
    long off = ((long)b * NN + i) * HD + d;
    if (APPLY_BN) {
      xbo[off] = f2b(fmaxf(fmaf(val, sc, sh), 0.f));
    } else {
      xo[off] = val;
    }
  }
}

extern "C" void kernel_launch(void* const* d_in, const int* in_sizes, int n_in,
                              void* d_out, int out_size, void* d_ws,
                              size_t ws_size, hipStream_t stream) {
  const float* locs = (const float*)d_in[0];
  const float* le_W0 = (const float*)d_in[1];
  const float* le_b0 = (const float*)d_in[2];
  const float* le_W1 = (const float*)d_in[3];
  const float* le_b1 = (const float*)d_in[4];
  const float* le_bn_g = (const float*)d_in[5];
  const float* le_bn_b = (const float*)d_in[6];
  const float* le_bn_m = (const float*)d_in[7];
  const float* le_bn_v = (const float*)d_in[8];
  const float* le_Wo = (const float*)d_in[9];
  const float* le_bo = (const float*)d_in[10];
  const float* gat_W = (const float*)d_in[11];
  const float* gat_asrc = (const float*)d_in[12];
  const float* gat_adst = (const float*)d_in[13];
  const float* gat_b = (const float*)d_in[14];
  const float* bn_g = (const float*)d_in[15];
  const float* bn_b = (const float*)d_in[16];
  const float* bn_m = (const float*)d_in[17];
  const float* bn_v = (const float*)d_in[18];

  float* out = (float*)d_out;                          // final f32 output
  unsigned short* hb = (unsigned short*)d_ws;          // 8,192,000 bf16
  unsigned short* hs = hb + 8192000;                   // 8,192,000 bf16
  unsigned short* xb = hs + 8192000;                   // 8,192,000 bf16
  unsigned short* WT = xb + 8192000;                   // 49,152 bf16 (+pad)
  float* C1 = (float*)(WT + 49152 + 64);               // 1,032,192 f32
  float* C2 = C1 + 1032192;                            // 1,032,192
  float* es = C2 + 1032192;
  float* ed = es + 64000;
  float2* e12 = (float2*)(ed + 64000);                 // 64,000 float2
  float2* ab = e12 + 64000;                            // 64,000 float2
  int* perm = (int*)(ab + 64000);
  int* kcut = perm + 64000;
  // total ≈ 59.3 MB << ws (~256 MB per fillBuffer WRITE_SIZE)

  k_embed<<<1000, 256, 0, stream>>>(locs, le_W0, le_b0, le_W1, le_b1, le_bn_g,
                                    le_bn_b, le_bn_m, le_bn_v, le_Wo, le_bo,
                                    gat_W, WT, xb);
  for (int l = 0; l < 3; ++l) {
    k_gemm_e<<<1000, 256, 0, stream>>>(xb, WT + l * 16384,
                                       gat_asrc + l * 128, gat_adst + l * 128,
                                       hb, es, ed);
    k_sort<<<NB, 512, 0, stream>>>(es, ed, e12, perm, kcut, ab);
    k_cpfx<<<dim3(NB, 4), 256, 0, stream>>>(hb, e12, perm, C1, C2, hs);
    if (l < 2) {
      k_out<true><<<dim3(NB, NC), 128, 0, stream>>>(
          hs, C1, C2, e12, kcut, ab, gat_b + l * 128, bn_g + l * 128,
          bn_b + l * 128, bn_m + l * 128, bn_v + l * 128, nullptr, xb);
    } else {
      k_out<false><<<dim3(NB, NC), 128, 0, stream>>>(
          hs, C1, C2, e12, kcut, ab, gat_b + 2 * 128, nullptr, nullptr,
          nullptr, nullptr, out, nullptr);
    }
  }
}

// Round 15
// 209.810 us; speedup vs baseline: 1.7321x; 1.1257x over previous
//
#include <hip/hip_runtime.h>
#include <hip/hip_bf16.h>

#define BN_EPS 1e-5f
#define NB 64
#define NN 1000
#define NP 1024
#define HD 128
#define CS 8
#define NC 125  // NN/CS exactly

typedef short bf16x8 __attribute__((ext_vector_type(8)));
typedef float f32x4 __attribute__((ext_vector_type(4)));

__device__ __forceinline__ unsigned short f2b(float f) {
  __hip_bfloat16 h = __float2bfloat16(f);
  return *reinterpret_cast<unsigned short*>(&h);
}
__device__ __forceinline__ float b2f(unsigned short u) {
  unsigned v = ((unsigned)u) << 16;
  return __uint_as_float(v);
}
// monotonic float -> uint (unsigned compare == float compare)
__device__ __forceinline__ unsigned tkey(float f) {
  unsigned u = __float_as_uint(f);
  return u ^ ((unsigned)((int)u >> 31) | 0x80000000u);
}
__device__ __forceinline__ float tdec(unsigned m) {
  unsigned u = (m & 0x80000000u) ? (m ^ 0x80000000u) : ~m;
  return __uint_as_float(u);
}

// ---------------------------------------------------------------------------
// Embedding MLP, register-tiled. 64 nodes/block. Writes xb (bf16).
// Blocks 0..191 also transpose the 3 GAT weights into WT (bf16).
// ---------------------------------------------------------------------------
__global__ __launch_bounds__(256) void k_embed(
    const float* __restrict__ locs,
    const float* __restrict__ W0, const float* __restrict__ b0,
    const float* __restrict__ W1, const float* __restrict__ b1,
    const float* __restrict__ g1, const float* __restrict__ be1,
    const float* __restrict__ m1, const float* __restrict__ v1,
    const float* __restrict__ Wo, const float* __restrict__ bo,
    const float* __restrict__ gatW, unsigned short* __restrict__ WT,
    unsigned short* __restrict__ xb) {
  __shared__ float z1T[64][68];
  __shared__ float z2T[64][68];
  int tid = threadIdx.x;
  long base = (long)blockIdx.x * 64;

  if (blockIdx.x < 192) {  // fused W transpose: 49152 elems
    int idx = blockIdx.x * 256 + tid;
    int lay = idx >> 14, rem = idx & 16383;
    int n = rem >> 7, kk = rem & 127;
    WT[idx] = f2b(gatW[lay * 16384 + kk * 128 + n]);
  }

  {
    int d = tid & 63;
    int q = tid >> 6;
    float w0x = W0[d], w0y = W0[64 + d], bb = b0[d];
#pragma unroll
    for (int g = 0; g < 4; ++g) {
      float vv[4];
#pragma unroll
      for (int i = 0; i < 4; ++i) {
        int n = g * 16 + q * 4 + i;
        float lx = locs[(base + n) * 2 + 0];
        float ly = locs[(base + n) * 2 + 1];
        vv[i] = fmaxf(fmaf(lx, w0x, fmaf(ly, w0y, bb)), 0.f);
      }
      *(float4*)&z1T[d][g * 16 + q * 4] = make_float4(vv[0], vv[1], vv[2], vv[3]);
    }
  }
  __syncthreads();

  int nt = tid & 15;
  int dt = tid >> 4;

  {
    float acc[4][4];
#pragma unroll
    for (int i = 0; i < 4; ++i)
#pragma unroll
      for (int j = 0; j < 4; ++j) acc[i][j] = 0.f;
#pragma unroll 4
    for (int k = 0; k < 64; ++k) {
      float4 zv = *(const float4*)&z1T[k][4 * nt];
      float4 wv = *(const float4*)&W1[k * 64 + 4 * dt];
      float zz[4] = {zv.x, zv.y, zv.z, zv.w};
      float ww[4] = {wv.x, wv.y, wv.z, wv.w};
#pragma unroll
      for (int i = 0; i < 4; ++i)
#pragma unroll
        for (int j = 0; j < 4; ++j) acc[i][j] = fmaf(zz[i], ww[j], acc[i][j]);
    }
    float4 b1v = *(const float4*)&b1[4 * dt];
    float4 g1v = *(const float4*)&g1[4 * dt];
    float4 bev = *(const float4*)&be1[4 * dt];
    float4 m1v = *(const float4*)&m1[4 * dt];
    float4 v1v = *(const float4*)&v1[4 * dt];
    float bbv[4] = {b1v.x, b1v.y, b1v.z, b1v.w};
    float ggv[4] = {g1v.x, g1v.y, g1v.z, g1v.w};
    float eev[4] = {bev.x, bev.y, bev.z, bev.w};
    float mmv[4] = {m1v.x, m1v.y, m1v.z, m1v.w};
    float vvv[4] = {v1v.x, v1v.y, v1v.z, v1v.w};
#pragma unroll
    for (int j = 0; j < 4; ++j) {
      float sc = ggv[j] * rsqrtf(vvv[j] + BN_EPS);
      float sh = eev[j] - mmv[j] * sc;
      float o[4];
#pragma unroll
      for (int i = 0; i < 4; ++i)
        o[i] = fmaxf(fmaf(acc[i][j] + bbv[j], sc, sh), 0.f);
      *(float4*)&z2T[4 * dt + j][4 * nt] = make_float4(o[0], o[1], o[2], o[3]);
    }
  }
  __syncthreads();

  {
    float acc[4][8];
#pragma unroll
    for (int i = 0; i < 4; ++i)
#pragma unroll
      for (int j = 0; j < 8; ++j) acc[i][j] = 0.f;
#pragma unroll 2
    for (int k = 0; k < 64; ++k) {
      float4 zv = *(const float4*)&z2T[k][4 * nt];
      float4 wa = *(const float4*)&Wo[k * 128 + 4 * dt];
      float4 wb = *(const float4*)&Wo[k * 128 + 64 + 4 * dt];
      float zz[4] = {zv.x, zv.y, zv.z, zv.w};
      float w0[4] = {wa.x, wa.y, wa.z, wa.w};
      float w1[4] = {wb.x, wb.y, wb.z, wb.w};
#pragma unroll
      for (int i = 0; i < 4; ++i) {
#pragma unroll
        for (int j = 0; j < 4; ++j) {
          acc[i][j] = fmaf(zz[i], w0[j], acc[i][j]);
          acc[i][4 + j] = fmaf(zz[i], w1[j], acc[i][4 + j]);
        }
      }
    }
    float4 bo0 = *(const float4*)&bo[4 * dt];
    float4 bo1 = *(const float4*)&bo[64 + 4 * dt];
    float bb0[4] = {bo0.x, bo0.y, bo0.z, bo0.w};
    float bb1[4] = {bo1.x, bo1.y, bo1.z, bo1.w};
#pragma unroll
    for (int i = 0; i < 4; ++i) {
      ushort4 p0, p1;
      p0.x = f2b(acc[i][0] + bb0[0]); p0.y = f2b(acc[i][1] + bb0[1]);
      p0.z = f2b(acc[i][2] + bb0[2]); p0.w = f2b(acc[i][3] + bb0[3]);
      p1.x = f2b(acc[i][4] + bb1[0]); p1.y = f2b(acc[i][5] + bb1[1]);
      p1.z = f2b(acc[i][6] + bb1[2]); p1.w = f2b(acc[i][7] + bb1[3]);
      *(ushort4*)&xb[(base + 4 * nt + i) * 128 + 4 * dt] = p0;
      *(ushort4*)&xb[(base + 4 * nt + i) * 128 + 64 + 4 * dt] = p1;
    }
  }
}

// ---------------------------------------------------------------------------
// h = xb @ W via MFMA 16x16x32 bf16. No LDS. Block = 4 waves, wave = 16 rows.
// Writes hb (bf16); e_src/e_dst dots from f32 accumulators.
// ---------------------------------------------------------------------------
__global__ __launch_bounds__(256) void k_gemm_e(
    const unsigned short* __restrict__ xb, const unsigned short* __restrict__ WT,
    const float* __restrict__ asrc, const float* __restrict__ adst,
    unsigned short* __restrict__ hb, float* __restrict__ es,
    float* __restrict__ ed) {
  int tid = threadIdx.x;
  int w = tid >> 6, l = tid & 63;
  long rowbase = (long)blockIdx.x * 64 + w * 16;
  int r = l & 15, g = l >> 4;

  f32x4 acc[8];
#pragma unroll
  for (int n = 0; n < 8; ++n) acc[n] = {0.f, 0.f, 0.f, 0.f};

#pragma unroll
  for (int ks = 0; ks < 4; ++ks) {
    bf16x8 a = *(const bf16x8*)&xb[(rowbase + r) * 128 + ks * 32 + g * 8];
#pragma unroll
    for (int n = 0; n < 8; ++n) {
      bf16x8 bfr = *(const bf16x8*)&WT[(n * 16 + r) * 128 + ks * 32 + g * 8];
      acc[n] = __builtin_amdgcn_mfma_f32_16x16x32_bf16(a, bfr, acc[n], 0, 0, 0);
    }
  }

  float ps[4] = {0.f, 0.f, 0.f, 0.f};
  float pd[4] = {0.f, 0.f, 0.f, 0.f};
#pragma unroll
  for (int n = 0; n < 8; ++n) {
    float sa = asrc[n * 16 + r];
    float sd = adst[n * 16 + r];
#pragma unroll
    for (int rr = 0; rr < 4; ++rr) {
      float v = acc[n][rr];
      hb[(rowbase + g * 4 + rr) * 128 + n * 16 + r] = f2b(v);
      ps[rr] = fmaf(v, sa, ps[rr]);
      pd[rr] = fmaf(v, sd, pd[rr]);
    }
  }
#pragma unroll
  for (int rr = 0; rr < 4; ++rr) {
#pragma unroll
    for (int m = 1; m <= 8; m <<= 1) {
      ps[rr] += __shfl_xor(ps[rr], m, 64);
      pd[rr] += __shfl_xor(pd[rr], m, 64);
    }
  }
  if (r == 0) {
#pragma unroll
    for (int rr = 0; rr < 4; ++rr) {
      es[rowbase + g * 4 + rr] = ps[rr];
      ed[rowbase + g * 4 + rr] = pd[rr];
    }
  }
}

#define CEX(a, b, up)                         \
  do {                                        \
    if (((a) > (b)) == (up)) {                \
      unsigned long long _t = (a);            \
      (a) = (b);                              \
      (b) = _t;                               \
    }                                         \
  } while (0)

// ---------------------------------------------------------------------------
// Fused sort + scan + coeffs + chunk-sums + chunk-prefix + sorted-h emission.
// grid (NB, 4), 512 threads; block = (batch b, 32-dim slice dq). Each block
// redundantly sorts batch b in LDS (4 copies run concurrently), then:
//  B: shfl scan of (e1,e2) -> sc (overlay region); dq==0 writes e12.
//  C: dq==0 only: per-target binsearch -> kcut + (alpha,beta).
//  D: chunk gather via LDS keys (no global perm), write hs + s1/s2 (overlay).
//  E: serial exclusive chunk prefix (+ totals). F: coalesced C store.
// e1/e2 recomputed from decoded keys are bit-identical everywhere.
// ---------------------------------------------------------------------------
__global__ __launch_bounds__(512) void k_scpfx(
    const float* __restrict__ es, const float* __restrict__ ed,
    const unsigned short* __restrict__ hb, float2* __restrict__ e12,
    int* __restrict__ kcut, float2* __restrict__ ab, float* __restrict__ C1,
    float* __restrict__ C2, unsigned short* __restrict__ hs) {
  __shared__ unsigned long long keys[NP];      // 8192 B, live A..D
  __shared__ float smem[(NC + 1) * 64];        // 32256 B overlay: sc | s1,s2
  __shared__ float2 wtot[8];
  float2* sc = (float2*)smem;                  // 1000 float2 (B..C)
  float (*s1)[32] = (float(*)[32])smem;        // 126x32 (D..F)
  float (*s2)[32] = (float(*)[32])(smem + (NC + 1) * 32);
  int tid = threadIdx.x, b = blockIdx.x, dq = blockIdx.y;

  // ---- A: load + u64 bitonic sort ----
  for (int i = tid; i < NP; i += 512) {
    unsigned long long kk;
    if (i < NN) {
      kk = ((unsigned long long)tkey(es[b * NN + i]) << 32) | (unsigned)i;
    } else {
      kk = (0xFF800000ull << 32) | (unsigned)i;  // tkey(+INF) pad
    }
    keys[i] = kk;
  }
  __syncthreads();
  int i0 = tid * 2;
  {
    unsigned long long q0 = keys[i0], q1 = keys[i0 + 1];
    CEX(q0, q1, (i0 & 2) == 0);
    keys[i0] = q0; keys[i0 + 1] = q1;
  }
  __syncthreads();
  for (int k = 4; k <= NP; k <<= 1) {
    for (int j = k >> 1; j >= 2; j >>= 1) {
      int i = ((tid & ~(j - 1)) << 1) | (tid & (j - 1));
      int ixj = i | j;
      bool up = ((i & k) == 0);
      unsigned long long a = keys[i], c = keys[ixj];
      if ((a > c) == up) { keys[i] = c; keys[ixj] = a; }
      __syncthreads();
    }
    {
      unsigned long long q0 = keys[i0], q1 = keys[i0 + 1];
      CEX(q0, q1, (i0 & k) == 0);
      keys[i0] = q0; keys[i0 + 1] = q1;
    }
    __syncthreads();
  }

  // ---- B: decode + hierarchical scan of (e1,e2) -> sc ----
  float2 f0 = make_float2(0.f, 0.f), f1 = make_float2(0.f, 0.f);
  {
    unsigned long long k0 = keys[i0], k1 = keys[i0 + 1];
    if (i0 < NN) {
      float s = tdec((unsigned)(k0 >> 32));
      f0.x = __expf(s);
      f0.y = __expf(0.2f * s);
      if (dq == 0) e12[b * NN + i0] = f0;
    }
    if (i0 + 1 < NN) {
      float s = tdec((unsigned)(k1 >> 32));
      f1.x = __expf(s);
      f1.y = __expf(0.2f * s);
      if (dq == 0) e12[b * NN + i0 + 1] = f1;
    }
  }
  int lane = tid & 63, wid = tid >> 6;
  float tx = f0.x + f1.x, ty = f0.y + f1.y;
  float ix = tx, iy = ty;
#pragma unroll
  for (int dlt = 1; dlt < 64; dlt <<= 1) {
    float ox = __shfl_up(ix, dlt, 64);
    float oy = __shfl_up(iy, dlt, 64);
    if (lane >= dlt) { ix += ox; iy += oy; }
  }
  if (lane == 63) wtot[wid] = make_float2(ix, iy);
  __syncthreads();
  float bx = 0.f, by = 0.f;
#pragma unroll
  for (int ww = 0; ww < 8; ++ww) {
    if (ww < wid) {
      float2 t = wtot[ww];
      bx += t.x;
      by += t.y;
    }
  }
  float exx = bx + ix - tx, eyy = by + iy - ty;  // exclusive at i0
  float in0x = exx + f0.x, in0y = eyy + f0.y;
  if (i0 < NN) sc[i0] = make_float2(in0x, in0y);
  if (i0 + 1 < NN) sc[i0 + 1] = make_float2(in0x + f1.x, in0y + f1.y);
  __syncthreads();

  // ---- C: per-target coefficients (dq==0 only) ----
  if (dq == 0) {
    float s1tot = sc[NN - 1].x;
    for (int i = tid; i < NN; i += 512) {
      float di = ed[b * NN + i];
      unsigned tt = tkey(-di);
      int lo = 0, hi = NP;
      while (lo < hi) {
        int mid = (lo + hi) >> 1;
        if ((unsigned)(keys[mid] >> 32) <= tt) lo = mid + 1; else hi = mid;
      }
      int k = lo;  // #{s_j <= t_i} <= NN (pads are +INF)
      float p1 = (k > 0) ? sc[k - 1].x : 0.f;
      float p2 = (k > 0) ? sc[k - 1].y : 0.f;
      float Ed = __expf(di);
      float Ed2 = __expf(0.2f * di);
      float den = fmaf(Ed, s1tot - p1, Ed2 * p2);
      kcut[b * NN + i] = k;
      ab[b * NN + i] = make_float2(Ed / den, Ed2 / den);
    }
  }
  __syncthreads();  // sc dead after this; s1/s2 may overwrite

  // ---- D: chunk gather via LDS keys; write hs + chunk sums ----
  int d = tid & 31;
  int cl = tid >> 5;  // chunk lane 0..15
  int dglob = dq * 32 + d;
  for (int c = cl; c < NC; c += 16) {
    float v1 = 0.f, v2 = 0.f;
#pragma unroll
    for (int u = 0; u < CS; ++u) {
      int j = c * CS + u;
      unsigned long long kk = keys[j];
      int p = (int)(unsigned)kk;
      float s = tdec((unsigned)(kk >> 32));
      float e1 = __expf(s), e2 = __expf(0.2f * s);
      unsigned short hraw = hb[((long)b * NN + p) * HD + dglob];
      hs[((long)b * NN + j) * HD + dglob] = hraw;
      float hv = b2f(hraw);
      v1 = fmaf(e1, hv, v1);
      v2 = fmaf(e2, hv, v2);
    }
    s1[c][d] = v1;
    s2[c][d] = v2;
  }
  __syncthreads();

  // ---- E: serial exclusive chunk prefix (+ totals) ----
  if (tid < 32) {
    float r = 0.f;
    for (int c = 0; c < NC; ++c) {
      float v = s1[c][tid];
      s1[c][tid] = r;
      r += v;
    }
    s1[NC][tid] = r;
  } else if (tid < 64) {
    int dd = tid - 32;
    float r = 0.f;
    for (int c = 0; c < NC; ++c) {
      float v = s2[c][dd];
      s2[c][dd] = r;
      r += v;
    }
    s2[NC][dd] = r;
  }
  __syncthreads();

  // ---- F: coalesced C store ----
  long basec = (long)b * (NC + 1) * HD + dq * 32;
  for (int i = tid; i < (NC + 1) * 32; i += 512) {
    int c = i >> 5, dd = i & 31;
    C1[basec + (long)c * HD + dd] = s1[c][dd];
    C2[basec + (long)c * HD + dd] = s2[c][dd];
  }
}

// ---------------------------------------------------------------------------
// out[i] = a_i*(T1 - C1[c_i] - res1) + b_i*(C2[c_i] + res2) + bias.
// Residual reads hs (sorted-order, consecutive rows, no indirection).
// APPLY_BN=true: writes bf16 xb (intermediate); false: writes f32 out.
// ---------------------------------------------------------------------------
template <bool APPLY_BN>
__global__ __launch_bounds__(128) void k_out(
    const unsigned short* __restrict__ hs, const float* __restrict__ C1,
    const float* __restrict__ C2, const float2* __restrict__ e12,
    const int* __restrict__ kcut, const float2* __restrict__ ab,
    const float* __restrict__ bias, const float* __restrict__ bng,
    const float* __restrict__ bnb, const float* __restrict__ bnm,
    const float* __restrict__ bnv, float* __restrict__ xo,
    unsigned short* __restrict__ xbo) {
  int d = threadIdx.x, b = blockIdx.x;
  int i0 = blockIdx.y * 8;
  float T1 = C1[((long)b * (NC + 1) + NC) * HD + d];
  float bs = bias[d];
  float sc = 0.f, sh = 0.f;
  if (APPLY_BN) {
    float g = bng[d], bb = bnb[d], m = bnm[d], v = bnv[d];
    sc = g * rsqrtf(v + BN_EPS);
    sh = bb - m * sc;
  }
  for (int i = i0; i < i0 + 8; ++i) {
    int k = kcut[b * NN + i];
    float2 coeff = ab[b * NN + i];
    int c = k >> 3;
    float base1 = C1[((long)b * (NC + 1) + c) * HD + d];
    float base2 = C2[((long)b * (NC + 1) + c) * HD + d];
    float p1 = 0.f, p2 = 0.f;
    for (int j = c * CS; j < k; ++j) {
      float hv = b2f(hs[((long)b * NN + j) * HD + d]);
      float2 e = e12[b * NN + j];
      p1 = fmaf(e.x, hv, p1);
      p2 = fmaf(e.y, hv, p2);
    }
    float val = fmaf(coeff.x, T1 - base1 - p1, fmaf(coeff.y, base2 + p2, bs));
    long off = ((long)b * NN + i) * HD + d;
    if (APPLY_BN) {
      xbo[off] = f2b(fmaxf(fmaf(val, sc, sh), 0.f));
    } else {
      xo[off] = val;
    }
  }
}

extern "C" void kernel_launch(void* const* d_in, const int* in_sizes, int n_in,
                              void* d_out, int out_size, void* d_ws,
                              size_t ws_size, hipStream_t stream) {
  const float* locs = (const float*)d_in[0];
  const float* le_W0 = (const float*)d_in[1];
  const float* le_b0 = (const float*)d_in[2];
  const float* le_W1 = (const float*)d_in[3];
  const float* le_b1 = (const float*)d_in[4];
  const float* le_bn_g = (const float*)d_in[5];
  const float* le_bn_b = (const float*)d_in[6];
  const float* le_bn_m = (const float*)d_in[7];
  const float* le_bn_v = (const float*)d_in[8];
  const float* le_Wo = (const float*)d_in[9];
  const float* le_bo = (const float*)d_in[10];
  const float* gat_W = (const float*)d_in[11];
  const float* gat_asrc = (const float*)d_in[12];
  const float* gat_adst = (const float*)d_in[13];
  const float* gat_b = (const float*)d_in[14];
  const float* bn_g = (const float*)d_in[15];
  const float* bn_b = (const float*)d_in[16];
  const float* bn_m = (const float*)d_in[17];
  const float* bn_v = (const float*)d_in[18];

  float* out = (float*)d_out;                          // final f32 output
  unsigned short* hb = (unsigned short*)d_ws;          // 8,192,000 bf16
  unsigned short* hs = hb + 8192000;                   // 8,192,000 bf16
  unsigned short* xb = hs + 8192000;                   // 8,192,000 bf16
  unsigned short* WT = xb + 8192000;                   // 49,152 bf16 (+pad)
  float* C1 = (float*)(WT + 49152 + 64);               // 1,032,192 f32
  float* C2 = C1 + 1032192;                            // 1,032,192
  float* es = C2 + 1032192;
  float* ed = es + 64000;
  float2* e12 = (float2*)(ed + 64000);                 // 64,000 float2
  float2* ab = e12 + 64000;                            // 64,000 float2
  int* kcut = (int*)(ab + 64000);
  // total ≈ 59 MB << ws

  k_embed<<<1000, 256, 0, stream>>>(locs, le_W0, le_b0, le_W1, le_b1, le_bn_g,
                                    le_bn_b, le_bn_m, le_bn_v, le_Wo, le_bo,
                                    gat_W, WT, xb);
  for (int l = 0; l < 3; ++l) {
    k_gemm_e<<<1000, 256, 0, stream>>>(xb, WT + l * 16384,
                                       gat_asrc + l * 128, gat_adst + l * 128,
                                       hb, es, ed);
    k_scpfx<<<dim3(NB, 4), 512, 0, stream>>>(es, ed, hb, e12, kcut, ab, C1,
                                             C2, hs);
    if (l < 2) {
      k_out<true><<<dim3(NB, NC), 128, 0, stream>>>(
          hs, C1, C2, e12, kcut, ab, gat_b + l * 128, bn_g + l * 128,
          bn_b + l * 128, bn_m + l * 128, bn_v + l * 128, nullptr, xb);
    } else {
      k_out<false><<<dim3(NB, NC), 128, 0, stream>>>(
          hs, C1, C2, e12, kcut, ab, gat_b + 2 * 128, nullptr, nullptr,
          nullptr, nullptr, out, nullptr);
    }
  }
}

// Round 16
// 206.816 us; speedup vs baseline: 1.7572x; 1.0145x over previous
//
#include <hip/hip_runtime.h>
#include <hip/hip_bf16.h>

#define BN_EPS 1e-5f
#define NB 64
#define NN 1000
#define NP 1024
#define HD 128
#define CS 8
#define NC 125  // NN/CS exactly
#define XS 136  // LDS x-tile stride (shorts): 8B-aligned rows, near-optimal banks

typedef short bf16x8 __attribute__((ext_vector_type(8)));
typedef float f32x4 __attribute__((ext_vector_type(4)));

__device__ __forceinline__ unsigned short f2b(float f) {
  __hip_bfloat16 h = __float2bfloat16(f);
  return *reinterpret_cast<unsigned short*>(&h);
}
__device__ __forceinline__ float b2f(unsigned short u) {
  unsigned v = ((unsigned)u) << 16;
  return __uint_as_float(v);
}
// monotonic float -> uint (unsigned compare == float compare)
__device__ __forceinline__ unsigned tkey(float f) {
  unsigned u = __float_as_uint(f);
  return u ^ ((unsigned)((int)u >> 31) | 0x80000000u);
}
__device__ __forceinline__ float tdec(unsigned m) {
  unsigned u = (m & 0x80000000u) ? (m ^ 0x80000000u) : ~m;
  return __uint_as_float(u);
}

// ---------------------------------------------------------------------------
// WT[l][n][k] = bf16(W[l][k][n]) for the 3 GAT layers. 49152 elems.
// ---------------------------------------------------------------------------
__global__ __launch_bounds__(256) void k_wprep(const float* __restrict__ W,
                                               unsigned short* __restrict__ WT) {
  int idx = blockIdx.x * 256 + threadIdx.x;
  int lay = idx >> 14, rem = idx & 16383;
  int n = rem >> 7, k = rem & 127;
  WT[idx] = f2b(W[lay * 16384 + k * 128 + n]);
}

// ---------------------------------------------------------------------------
// FUSED embed MLP + layer-0 GEMM+e. Grid 1000x256; block owns rows 64i..64i+63
// in BOTH the embed output and the GEMM input -> x tile stays in LDS (bf16),
// never touches global. Phases: A locs->z1T, B z1T->z2T, C z2T->xs (bf16 LDS,
// overlays z1T), D MFMA (A-frags from LDS, B-frags from WT0) + h/es/ed.
// ---------------------------------------------------------------------------
__global__ __launch_bounds__(256) void k_embed_gemm(
    const float* __restrict__ locs,
    const float* __restrict__ W0, const float* __restrict__ b0,
    const float* __restrict__ W1, const float* __restrict__ b1,
    const float* __restrict__ g1, const float* __restrict__ be1,
    const float* __restrict__ m1, const float* __restrict__ v1,
    const float* __restrict__ Wo, const float* __restrict__ bo,
    const unsigned short* __restrict__ WT,
    const float* __restrict__ asrc, const float* __restrict__ adst,
    unsigned short* __restrict__ hb, float* __restrict__ es,
    float* __restrict__ ed) {
  __shared__ float z1T[64][68];   // phase A/B; phase C overlays xs here
  __shared__ float z2T[64][68];
  unsigned short* xs = (unsigned short*)&z1T[0][0];  // [64][XS=136] = 17408 B
  int tid = threadIdx.x;
  long base = (long)blockIdx.x * 64;

  // ---- A ----
  {
    int d = tid & 63;
    int q = tid >> 6;
    float w0x = W0[d], w0y = W0[64 + d], bb = b0[d];
#pragma unroll
    for (int g = 0; g < 4; ++g) {
      float vv[4];
#pragma unroll
      for (int i = 0; i < 4; ++i) {
        int n = g * 16 + q * 4 + i;
        float lx = locs[(base + n) * 2 + 0];
        float ly = locs[(base + n) * 2 + 1];
        vv[i] = fmaxf(fmaf(lx, w0x, fmaf(ly, w0y, bb)), 0.f);
      }
      *(float4*)&z1T[d][g * 16 + q * 4] = make_float4(vv[0], vv[1], vv[2], vv[3]);
    }
  }
  __syncthreads();

  int nt = tid & 15;
  int dt = tid >> 4;

  // ---- B ----
  {
    float acc[4][4];
#pragma unroll
    for (int i = 0; i < 4; ++i)
#pragma unroll
      for (int j = 0; j < 4; ++j) acc[i][j] = 0.f;
#pragma unroll 4
    for (int k = 0; k < 64; ++k) {
      float4 zv = *(const float4*)&z1T[k][4 * nt];
      float4 wv = *(const float4*)&W1[k * 64 + 4 * dt];
      float zz[4] = {zv.x, zv.y, zv.z, zv.w};
      float ww[4] = {wv.x, wv.y, wv.z, wv.w};
#pragma unroll
      for (int i = 0; i < 4; ++i)
#pragma unroll
        for (int j = 0; j < 4; ++j) acc[i][j] = fmaf(zz[i], ww[j], acc[i][j]);
    }
    float4 b1v = *(const float4*)&b1[4 * dt];
    float4 g1v = *(const float4*)&g1[4 * dt];
    float4 bev = *(const float4*)&be1[4 * dt];
    float4 m1v = *(const float4*)&m1[4 * dt];
    float4 v1v = *(const float4*)&v1[4 * dt];
    float bbv[4] = {b1v.x, b1v.y, b1v.z, b1v.w};
    float ggv[4] = {g1v.x, g1v.y, g1v.z, g1v.w};
    float eev[4] = {bev.x, bev.y, bev.z, bev.w};
    float mmv[4] = {m1v.x, m1v.y, m1v.z, m1v.w};
    float vvv[4] = {v1v.x, v1v.y, v1v.z, v1v.w};
#pragma unroll
    for (int j = 0; j < 4; ++j) {
      float sc = ggv[j] * rsqrtf(vvv[j] + BN_EPS);
      float sh = eev[j] - mmv[j] * sc;
      float o[4];
#pragma unroll
      for (int i = 0; i < 4; ++i)
        o[i] = fmaxf(fmaf(acc[i][j] + bbv[j], sc, sh), 0.f);
      *(float4*)&z2T[4 * dt + j][4 * nt] = make_float4(o[0], o[1], o[2], o[3]);
    }
  }
  __syncthreads();  // all z1T reads done; xs may overlay

  // ---- C: x = z2 @ Wo + bo -> bf16 LDS tile ----
  {
    float acc[4][8];
#pragma unroll
    for (int i = 0; i < 4; ++i)
#pragma unroll
      for (int j = 0; j < 8; ++j) acc[i][j] = 0.f;
#pragma unroll 2
    for (int k = 0; k < 64; ++k) {
      float4 zv = *(const float4*)&z2T[k][4 * nt];
      float4 wa = *(const float4*)&Wo[k * 128 + 4 * dt];
      float4 wb = *(const float4*)&Wo[k * 128 + 64 + 4 * dt];
      float zz[4] = {zv.x, zv.y, zv.z, zv.w};
      float w0[4] = {wa.x, wa.y, wa.z, wa.w};
      float w1[4] = {wb.x, wb.y, wb.z, wb.w};
#pragma unroll
      for (int i = 0; i < 4; ++i) {
#pragma unroll
        for (int j = 0; j < 4; ++j) {
          acc[i][j] = fmaf(zz[i], w0[j], acc[i][j]);
          acc[i][4 + j] = fmaf(zz[i], w1[j], acc[i][4 + j]);
        }
      }
    }
    float4 bo0 = *(const float4*)&bo[4 * dt];
    float4 bo1 = *(const float4*)&bo[64 + 4 * dt];
    float bb0[4] = {bo0.x, bo0.y, bo0.z, bo0.w};
    float bb1[4] = {bo1.x, bo1.y, bo1.z, bo1.w};
#pragma unroll
    for (int i = 0; i < 4; ++i) {
      ushort4 p0, p1;
      p0.x = f2b(acc[i][0] + bb0[0]); p0.y = f2b(acc[i][1] + bb0[1]);
      p0.z = f2b(acc[i][2] + bb0[2]); p0.w = f2b(acc[i][3] + bb0[3]);
      p1.x = f2b(acc[i][4] + bb1[0]); p1.y = f2b(acc[i][5] + bb1[1]);
      p1.z = f2b(acc[i][6] + bb1[2]); p1.w = f2b(acc[i][7] + bb1[3]);
      *(ushort4*)&xs[(4 * nt + i) * XS + 4 * dt] = p0;
      *(ushort4*)&xs[(4 * nt + i) * XS + 64 + 4 * dt] = p1;
    }
  }
  __syncthreads();

  // ---- D: MFMA h = x @ W0gat, fused e dots ----
  {
    int w = tid >> 6, l = tid & 63;
    long rowbase = base + w * 16;
    int r = l & 15, g = l >> 4;
    f32x4 acc[8];
#pragma unroll
    for (int n = 0; n < 8; ++n) acc[n] = {0.f, 0.f, 0.f, 0.f};
#pragma unroll
    for (int ks = 0; ks < 4; ++ks) {
      bf16x8 a = *(const bf16x8*)&xs[(w * 16 + r) * XS + ks * 32 + g * 8];
#pragma unroll
      for (int n = 0; n < 8; ++n) {
        bf16x8 bfr = *(const bf16x8*)&WT[(n * 16 + r) * 128 + ks * 32 + g * 8];
        acc[n] = __builtin_amdgcn_mfma_f32_16x16x32_bf16(a, bfr, acc[n], 0, 0, 0);
      }
    }
    float ps[4] = {0.f, 0.f, 0.f, 0.f};
    float pd[4] = {0.f, 0.f, 0.f, 0.f};
#pragma unroll
    for (int n = 0; n < 8; ++n) {
      float sa = asrc[n * 16 + r];
      float sd = adst[n * 16 + r];
#pragma unroll
      for (int rr = 0; rr < 4; ++rr) {
        float v = acc[n][rr];
        hb[(rowbase + g * 4 + rr) * 128 + n * 16 + r] = f2b(v);
        ps[rr] = fmaf(v, sa, ps[rr]);
        pd[rr] = fmaf(v, sd, pd[rr]);
      }
    }
#pragma unroll
    for (int rr = 0; rr < 4; ++rr) {
#pragma unroll
      for (int m = 1; m <= 8; m <<= 1) {
        ps[rr] += __shfl_xor(ps[rr], m, 64);
        pd[rr] += __shfl_xor(pd[rr], m, 64);
      }
    }
    if (r == 0) {
#pragma unroll
      for (int rr = 0; rr < 4; ++rr) {
        es[rowbase + g * 4 + rr] = ps[rr];
        ed[rowbase + g * 4 + rr] = pd[rr];
      }
    }
  }
}

// ---------------------------------------------------------------------------
// h = xb @ W via MFMA 16x16x32 bf16 (layers 1,2). No LDS.
// ---------------------------------------------------------------------------
__global__ __launch_bounds__(256) void k_gemm_e(
    const unsigned short* __restrict__ xb, const unsigned short* __restrict__ WT,
    const float* __restrict__ asrc, const float* __restrict__ adst,
    unsigned short* __restrict__ hb, float* __restrict__ es,
    float* __restrict__ ed) {
  int tid = threadIdx.x;
  int w = tid >> 6, l = tid & 63;
  long rowbase = (long)blockIdx.x * 64 + w * 16;
  int r = l & 15, g = l >> 4;

  f32x4 acc[8];
#pragma unroll
  for (int n = 0; n < 8; ++n) acc[n] = {0.f, 0.f, 0.f, 0.f};

#pragma unroll
  for (int ks = 0; ks < 4; ++ks) {
    bf16x8 a = *(const bf16x8*)&xb[(rowbase + r) * 128 + ks * 32 + g * 8];
#pragma unroll
    for (int n = 0; n < 8; ++n) {
      bf16x8 bfr = *(const bf16x8*)&WT[(n * 16 + r) * 128 + ks * 32 + g * 8];
      acc[n] = __builtin_amdgcn_mfma_f32_16x16x32_bf16(a, bfr, acc[n], 0, 0, 0);
    }
  }

  float ps[4] = {0.f, 0.f, 0.f, 0.f};
  float pd[4] = {0.f, 0.f, 0.f, 0.f};
#pragma unroll
  for (int n = 0; n < 8; ++n) {
    float sa = asrc[n * 16 + r];
    float sd = adst[n * 16 + r];
#pragma unroll
    for (int rr = 0; rr < 4; ++rr) {
      float v = acc[n][rr];
      hb[(rowbase + g * 4 + rr) * 128 + n * 16 + r] = f2b(v);
      ps[rr] = fmaf(v, sa, ps[rr]);
      pd[rr] = fmaf(v, sd, pd[rr]);
    }
  }
#pragma unroll
  for (int rr = 0; rr < 4; ++rr) {
#pragma unroll
    for (int m = 1; m <= 8; m <<= 1) {
      ps[rr] += __shfl_xor(ps[rr], m, 64);
      pd[rr] += __shfl_xor(pd[rr], m, 64);
    }
  }
  if (r == 0) {
#pragma unroll
    for (int rr = 0; rr < 4; ++rr) {
      es[rowbase + g * 4 + rr] = ps[rr];
      ed[rowbase + g * 4 + rr] = pd[rr];
    }
  }
}

#define CEX(a, b, up)                         \
  do {                                        \
    if (((a) > (b)) == (up)) {                \
      unsigned long long _t = (a);            \
      (a) = (b);                              \
      (b) = _t;                               \
    }                                         \
  } while (0)

// ---------------------------------------------------------------------------
// Fused sort + scan + coeffs + chunk-sums + chunk-prefix + sorted-h emission.
// grid (NB, 4), 512 threads. C12 written interleaved (c1,c2) float2.
// ---------------------------------------------------------------------------
__global__ __launch_bounds__(512) void k_scpfx(
    const float* __restrict__ es, const float* __restrict__ ed,
    const unsigned short* __restrict__ hb, float2* __restrict__ e12,
    int* __restrict__ kcut, float2* __restrict__ ab, float2* __restrict__ C12,
    unsigned short* __restrict__ hs) {
  __shared__ unsigned long long keys[NP];      // 8192 B, live A..D
  __shared__ float smem[(NC + 1) * 64];        // 32256 B overlay: sc | s1,s2
  __shared__ float2 wtot[8];
  float2* sc = (float2*)smem;                  // 1000 float2 (B..C)
  float (*s1)[32] = (float(*)[32])smem;        // 126x32 (D..F)
  float (*s2)[32] = (float(*)[32])(smem + (NC + 1) * 32);
  int tid = threadIdx.x, b = blockIdx.x, dq = blockIdx.y;

  // ---- A: load + u64 bitonic sort ----
  for (int i = tid; i < NP; i += 512) {
    unsigned long long kk;
    if (i < NN) {
      kk = ((unsigned long long)tkey(es[b * NN + i]) << 32) | (unsigned)i;
    } else {
      kk = (0xFF800000ull << 32) | (unsigned)i;  // tkey(+INF) pad
    }
    keys[i] = kk;
  }
  __syncthreads();
  int i0 = tid * 2;
  {
    unsigned long long q0 = keys[i0], q1 = keys[i0 + 1];
    CEX(q0, q1, (i0 & 2) == 0);
    keys[i0] = q0; keys[i0 + 1] = q1;
  }
  __syncthreads();
  for (int k = 4; k <= NP; k <<= 1) {
    for (int j = k >> 1; j >= 2; j >>= 1) {
      int i = ((tid & ~(j - 1)) << 1) | (tid & (j - 1));
      int ixj = i | j;
      bool up = ((i & k) == 0);
      unsigned long long a = keys[i], c = keys[ixj];
      if ((a > c) == up) { keys[i] = c; keys[ixj] = a; }
      __syncthreads();
    }
    {
      unsigned long long q0 = keys[i0], q1 = keys[i0 + 1];
      CEX(q0, q1, (i0 & k) == 0);
      keys[i0] = q0; keys[i0 + 1] = q1;
    }
    __syncthreads();
  }

  // ---- B: decode + hierarchical scan of (e1,e2) -> sc ----
  float2 f0 = make_float2(0.f, 0.f), f1 = make_float2(0.f, 0.f);
  {
    unsigned long long k0 = keys[i0], k1 = keys[i0 + 1];
    if (i0 < NN) {
      float s = tdec((unsigned)(k0 >> 32));
      f0.x = __expf(s);
      f0.y = __expf(0.2f * s);
      if (dq == 0) e12[b * NN + i0] = f0;
    }
    if (i0 + 1 < NN) {
      float s = tdec((unsigned)(k1 >> 32));
      f1.x = __expf(s);
      f1.y = __expf(0.2f * s);
      if (dq == 0) e12[b * NN + i0 + 1] = f1;
    }
  }
  int lane = tid & 63, wid = tid >> 6;
  float tx = f0.x + f1.x, ty = f0.y + f1.y;
  float ix = tx, iy = ty;
#pragma unroll
  for (int dlt = 1; dlt < 64; dlt <<= 1) {
    float ox = __shfl_up(ix, dlt, 64);
    float oy = __shfl_up(iy, dlt, 64);
    if (lane >= dlt) { ix += ox; iy += oy; }
  }
  if (lane == 63) wtot[wid] = make_float2(ix, iy);
  __syncthreads();
  float bx = 0.f, by = 0.f;
#pragma unroll
  for (int ww = 0; ww < 8; ++ww) {
    if (ww < wid) {
      float2 t = wtot[ww];
      bx += t.x;
      by += t.y;
    }
  }
  float exx = bx + ix - tx, eyy = by + iy - ty;  // exclusive at i0
  float in0x = exx + f0.x, in0y = eyy + f0.y;
  if (i0 < NN) sc[i0] = make_float2(in0x, in0y);
  if (i0 + 1 < NN) sc[i0 + 1] = make_float2(in0x + f1.x, in0y + f1.y);
  __syncthreads();

  // ---- C: per-target coefficients (dq==0 only) ----
  if (dq == 0) {
    float s1tot = sc[NN - 1].x;
    for (int i = tid; i < NN; i += 512) {
      float di = ed[b * NN + i];
      unsigned tt = tkey(-di);
      int lo = 0, hi = NP;
      while (lo < hi) {
        int mid = (lo + hi) >> 1;
        if ((unsigned)(keys[mid] >> 32) <= tt) lo = mid + 1; else hi = mid;
      }
      int k = lo;  // #{s_j <= t_i} <= NN (pads are +INF)
      float p1 = (k > 0) ? sc[k - 1].x : 0.f;
      float p2 = (k > 0) ? sc[k - 1].y : 0.f;
      float Ed = __expf(di);
      float Ed2 = __expf(0.2f * di);
      float den = fmaf(Ed, s1tot - p1, Ed2 * p2);
      kcut[b * NN + i] = k;
      ab[b * NN + i] = make_float2(Ed / den, Ed2 / den);
    }
  }
  __syncthreads();  // sc dead after this; s1/s2 may overwrite

  // ---- D: chunk gather via LDS keys; write hs + chunk sums ----
  int d = tid & 31;
  int cl = tid >> 5;  // chunk lane 0..15
  int dglob = dq * 32 + d;
  for (int c = cl; c < NC; c += 16) {
    float v1 = 0.f, v2 = 0.f;
#pragma unroll
    for (int u = 0; u < CS; ++u) {
      int j = c * CS + u;
      unsigned long long kk = keys[j];
      int p = (int)(unsigned)kk;
      float s = tdec((unsigned)(kk >> 32));
      float e1 = __expf(s), e2 = __expf(0.2f * s);
      unsigned short hraw = hb[((long)b * NN + p) * HD + dglob];
      hs[((long)b * NN + j) * HD + dglob] = hraw;
      float hv = b2f(hraw);
      v1 = fmaf(e1, hv, v1);
      v2 = fmaf(e2, hv, v2);
    }
    s1[c][d] = v1;
    s2[c][d] = v2;
  }
  __syncthreads();

  // ---- E: serial exclusive chunk prefix (+ totals) ----
  if (tid < 32) {
    float r = 0.f;
    for (int c = 0; c < NC; ++c) {
      float v = s1[c][tid];
      s1[c][tid] = r;
      r += v;
    }
    s1[NC][tid] = r;
  } else if (tid < 64) {
    int dd = tid - 32;
    float r = 0.f;
    for (int c = 0; c < NC; ++c) {
      float v = s2[c][dd];
      s2[c][dd] = r;
      r += v;
    }
    s2[NC][dd] = r;
  }
  __syncthreads();

  // ---- F: coalesced interleaved C12 store ----
  long basec = (long)b * (NC + 1) * HD + dq * 32;
  for (int i = tid; i < (NC + 1) * 32; i += 512) {
    int c = i >> 5, dd = i & 31;
    C12[basec + (long)c * HD + dd] = make_float2(s1[c][dd], s2[c][dd]);
  }
}

// ---------------------------------------------------------------------------
// out[i] = a_i*(T1 - C1[c_i] - res1) + b_i*(C2[c_i] + res2) + bias.
// C12 interleaved; residual reads hs (sorted-order, streaming).
// ---------------------------------------------------------------------------
template <bool APPLY_BN>
__global__ __launch_bounds__(128) void k_out(
    const unsigned short* __restrict__ hs, const float2* __restrict__ C12,
    const float2* __restrict__ e12, const int* __restrict__ kcut,
    const float2* __restrict__ ab, const float* __restrict__ bias,
    const float* __restrict__ bng, const float* __restrict__ bnb,
    const float* __restrict__ bnm, const float* __restrict__ bnv,
    float* __restrict__ xo, unsigned short* __restrict__ xbo) {
  int d = threadIdx.x, b = blockIdx.x;
  int i0 = blockIdx.y * 8;
  float T1 = C12[((long)b * (NC + 1) + NC) * HD + d].x;
  float bs = bias[d];
  float sc = 0.f, sh = 0.f;
  if (APPLY_BN) {
    float g = bng[d], bb = bnb[d], m = bnm[d], v = bnv[d];
    sc = g * rsqrtf(v + BN_EPS);
    sh = bb - m * sc;
  }
  for (int i = i0; i < i0 + 8; ++i) {
    int k = kcut[b * NN + i];
    float2 coeff = ab[b * NN + i];
    int c = k >> 3;
    float2 base12 = C12[((long)b * (NC + 1) + c) * HD + d];
    float p1 = 0.f, p2 = 0.f;
    for (int j = c * CS; j < k; ++j) {
      float hv = b2f(hs[((long)b * NN + j) * HD + d]);
      float2 e = e12[b * NN + j];
      p1 = fmaf(e.x, hv, p1);
      p2 = fmaf(e.y, hv, p2);
    }
    float val = fmaf(coeff.x, T1 - base12.x - p1,
                     fmaf(coeff.y, base12.y + p2, bs));
    long off = ((long)b * NN + i) * HD + d;
    if (APPLY_BN) {
      xbo[off] = f2b(fmaxf(fmaf(val, sc, sh), 0.f));
    } else {
      xo[off] = val;
    }
  }
}

extern "C" void kernel_launch(void* const* d_in, const int* in_sizes, int n_in,
                              void* d_out, int out_size, void* d_ws,
                              size_t ws_size, hipStream_t stream) {
  const float* locs = (const float*)d_in[0];
  const float* le_W0 = (const float*)d_in[1];
  const float* le_b0 = (const float*)d_in[2];
  const float* le_W1 = (const float*)d_in[3];
  const float* le_b1 = (const float*)d_in[4];
  const float* le_bn_g = (const float*)d_in[5];
  const float* le_bn_b = (const float*)d_in[6];
  const float* le_bn_m = (const float*)d_in[7];
  const float* le_bn_v = (const float*)d_in[8];
  const float* le_Wo = (const float*)d_in[9];
  const float* le_bo = (const float*)d_in[10];
  const float* gat_W = (const float*)d_in[11];
  const float* gat_asrc = (const float*)d_in[12];
  const float* gat_adst = (const float*)d_in[13];
  const float* gat_b = (const float*)d_in[14];
  const float* bn_g = (const float*)d_in[15];
  const float* bn_b = (const float*)d_in[16];
  const float* bn_m = (const float*)d_in[17];
  const float* bn_v = (const float*)d_in[18];

  float* out = (float*)d_out;                          // final f32 output
  unsigned short* hb = (unsigned short*)d_ws;          // 8,192,000 bf16
  unsigned short* hs = hb + 8192000;                   // 8,192,000 bf16
  unsigned short* xb = hs + 8192000;                   // 8,192,000 bf16
  unsigned short* WT = xb + 8192000;                   // 49,152 bf16 (+pad)
  float2* C12 = (float2*)(WT + 49152 + 64);            // 1,032,192 float2
  float* es = (float*)(C12 + 1032192);
  float* ed = es + 64000;
  float2* e12 = (float2*)(ed + 64000);                 // 64,000 float2
  float2* ab = e12 + 64000;                            // 64,000 float2
  int* kcut = (int*)(ab + 64000);
  // total ≈ 59 MB << ws

  k_wprep<<<192, 256, 0, stream>>>(gat_W, WT);
  for (int l = 0; l < 3; ++l) {
    if (l == 0) {
      k_embed_gemm<<<1000, 256, 0, stream>>>(
          locs, le_W0, le_b0, le_W1, le_b1, le_bn_g, le_bn_b, le_bn_m,
          le_bn_v, le_Wo, le_bo, WT, gat_asrc, gat_adst, hb, es, ed);
    } else {
      k_gemm_e<<<1000, 256, 0, stream>>>(xb, WT + l * 16384,
                                         gat_asrc + l * 128,
                                         gat_adst + l * 128, hb, es, ed);
    }
    k_scpfx<<<dim3(NB, 4), 512, 0, stream>>>(es, ed, hb, e12, kcut, ab, C12,
                                             hs);
    if (l < 2) {
      k_out<true><<<dim3(NB, NC), 128, 0, stream>>>(
          hs, C12, e12, kcut, ab, gat_b + l * 128, bn_g + l * 128,
          bn_b + l * 128, bn_m + l * 128, bn_v + l * 128, nullptr, xb);
    } else {
      k_out<false><<<dim3(NB, NC), 128, 0, stream>>>(
          hs, C12, e12, kcut, ab, gat_b + 2 * 128, nullptr, nullptr, nullptr,
          nullptr, out, nullptr);
    }
  }
}

// Round 17
// 183.324 us; speedup vs baseline: 1.9824x; 1.1281x over previous
//
#include <hip/hip_runtime.h>
#include <hip/hip_bf16.h>

#define BN_EPS 1e-5f
#define NB 64
#define NN 1000
#define NP 1024
#define HD 128
#define CS 8
#define NC 125  // NN/CS exactly
#define ZS 72   // z1b/z2b LDS row stride (shorts): 144B = 9x16B, odd -> conflict-free

typedef short bf16x8 __attribute__((ext_vector_type(8)));
typedef float f32x4 __attribute__((ext_vector_type(4)));

__device__ __forceinline__ unsigned short f2b(float f) {
  __hip_bfloat16 h = __float2bfloat16(f);
  return *reinterpret_cast<unsigned short*>(&h);
}
__device__ __forceinline__ float b2f(unsigned short u) {
  unsigned v = ((unsigned)u) << 16;
  return __uint_as_float(v);
}
// monotonic float -> uint (unsigned compare == float compare)
__device__ __forceinline__ unsigned tkey(float f) {
  unsigned u = __float_as_uint(f);
  return u ^ ((unsigned)((int)u >> 31) | 0x80000000u);
}
__device__ __forceinline__ float tdec(unsigned m) {
  unsigned u = (m & 0x80000000u) ? (m ^ 0x80000000u) : ~m;
  return __uint_as_float(u);
}

// ---------------------------------------------------------------------------
// Prep: WT[l][n][k]=bf16(Wg[l][k][n]) (49152); W1T[n][k]=bf16(W1[k][n]) (4096);
// WoWgT[c][i]=bf16(sum_d Wo[i][d]*Wg0[d][c]) (8192); biash[c]=bo@Wg0 (128 f32).
// ---------------------------------------------------------------------------
__global__ __launch_bounds__(256) void k_wprep(
    const float* __restrict__ Wg, const float* __restrict__ W1,
    const float* __restrict__ Wo, const float* __restrict__ bo,
    unsigned short* __restrict__ WT, unsigned short* __restrict__ W1T,
    unsigned short* __restrict__ WoWgT, float* __restrict__ biash) {
  int idx = blockIdx.x * 256 + threadIdx.x;
  if (idx < 49152) {
    int lay = idx >> 14, rem = idx & 16383;
    int n = rem >> 7, k = rem & 127;
    WT[idx] = f2b(Wg[lay * 16384 + k * 128 + n]);
  } else if (idx < 53248) {
    int j = idx - 49152;
    int n = j >> 6, k = j & 63;
    W1T[j] = f2b(W1[k * 64 + n]);
  } else if (idx < 61440) {
    int j = idx - 53248;
    int c = j >> 6, i = j & 63;
    float acc = 0.f;
#pragma unroll 4
    for (int d = 0; d < 128; ++d)
      acc = fmaf(Wo[i * 128 + d], Wg[d * 128 + c], acc);
    WoWgT[j] = f2b(acc);  // WoWgT[c*64+i]
  } else if (idx < 61568) {
    int c = idx - 61440;
    float acc = 0.f;
#pragma unroll 4
    for (int d = 0; d < 128; ++d) acc = fmaf(bo[d], Wg[d * 128 + c], acc);
    biash[c] = acc;
  }
}

// ---------------------------------------------------------------------------
// FUSED embed MLP + layer-0 GEMM, MFMA throughout.
//  A: z1 = relu(locs@W0+b0) -> z1b (bf16 LDS [64][ZS])
//  B: z2 = relu(bn(z1@W1+b1)) via MFMA (A=z1b, B=W1T) -> z2b (bf16 LDS)
//  C: h  = z2@(Wo@Wg0) + biash via MFMA (A=z2b, B=WoWgT) -> hb + es/ed
// ---------------------------------------------------------------------------
__global__ __launch_bounds__(256) void k_embed_gemm(
    const float* __restrict__ locs,
    const float* __restrict__ W0, const float* __restrict__ b0,
    const float* __restrict__ b1, const float* __restrict__ g1,
    const float* __restrict__ be1, const float* __restrict__ m1,
    const float* __restrict__ v1, const unsigned short* __restrict__ W1T,
    const unsigned short* __restrict__ WoWgT, const float* __restrict__ biash,
    const float* __restrict__ asrc, const float* __restrict__ adst,
    unsigned short* __restrict__ hb, float* __restrict__ es,
    float* __restrict__ ed) {
  __shared__ __align__(16) unsigned short z1b[64 * ZS];
  __shared__ __align__(16) unsigned short z2b[64 * ZS];
  int tid = threadIdx.x;
  long base = (long)blockIdx.x * 64;

  // ---- A ----
  {
    int d = tid & 63;
    int q = tid >> 6;
    float w0x = W0[d], w0y = W0[64 + d], bb = b0[d];
#pragma unroll
    for (int g = 0; g < 4; ++g) {
#pragma unroll
      for (int i = 0; i < 4; ++i) {
        int n = g * 16 + q * 4 + i;
        float lx = locs[(base + n) * 2 + 0];
        float ly = locs[(base + n) * 2 + 1];
        z1b[n * ZS + d] = f2b(fmaxf(fmaf(lx, w0x, fmaf(ly, w0y, bb)), 0.f));
      }
    }
  }
  __syncthreads();

  int w = tid >> 6, l = tid & 63;
  int r = l & 15, g = l >> 4;

  // ---- B: z2 = relu(bn(z1 @ W1 + b1)), MFMA ----
  {
    f32x4 acc[4];
#pragma unroll
    for (int n = 0; n < 4; ++n) acc[n] = {0.f, 0.f, 0.f, 0.f};
#pragma unroll
    for (int ks = 0; ks < 2; ++ks) {
      bf16x8 a = *(const bf16x8*)&z1b[(w * 16 + r) * ZS + ks * 32 + g * 8];
#pragma unroll
      for (int n = 0; n < 4; ++n) {
        bf16x8 bfr = *(const bf16x8*)&W1T[(n * 16 + r) * 64 + ks * 32 + g * 8];
        acc[n] = __builtin_amdgcn_mfma_f32_16x16x32_bf16(a, bfr, acc[n], 0, 0, 0);
      }
    }
#pragma unroll
    for (int n = 0; n < 4; ++n) {
      int col = n * 16 + r;
      float sc = g1[col] * rsqrtf(v1[col] + BN_EPS);
      float sh = be1[col] - m1[col] * sc;
      float bb = b1[col];
#pragma unroll
      for (int rr = 0; rr < 4; ++rr) {
        float v = fmaxf(fmaf(acc[n][rr] + bb, sc, sh), 0.f);
        z2b[(w * 16 + g * 4 + rr) * ZS + col] = f2b(v);
      }
    }
  }
  __syncthreads();

  // ---- C: h = z2 @ WoWg + biash, MFMA; fused e dots ----
  {
    long rowbase = base + w * 16;
    f32x4 acc[8];
#pragma unroll
    for (int n = 0; n < 8; ++n) acc[n] = {0.f, 0.f, 0.f, 0.f};
#pragma unroll
    for (int ks = 0; ks < 2; ++ks) {
      bf16x8 a = *(const bf16x8*)&z2b[(w * 16 + r) * ZS + ks * 32 + g * 8];
#pragma unroll
      for (int n = 0; n < 8; ++n) {
        bf16x8 bfr = *(const bf16x8*)&WoWgT[(n * 16 + r) * 64 + ks * 32 + g * 8];
        acc[n] = __builtin_amdgcn_mfma_f32_16x16x32_bf16(a, bfr, acc[n], 0, 0, 0);
      }
    }
    float ps[4] = {0.f, 0.f, 0.f, 0.f};
    float pd[4] = {0.f, 0.f, 0.f, 0.f};
#pragma unroll
    for (int n = 0; n < 8; ++n) {
      int col = n * 16 + r;
      float bh = biash[col];
      float sa = asrc[col];
      float sd = adst[col];
#pragma unroll
      for (int rr = 0; rr < 4; ++rr) {
        float v = acc[n][rr] + bh;
        hb[(rowbase + g * 4 + rr) * 128 + col] = f2b(v);
        ps[rr] = fmaf(v, sa, ps[rr]);
        pd[rr] = fmaf(v, sd, pd[rr]);
      }
    }
#pragma unroll
    for (int rr = 0; rr < 4; ++rr) {
#pragma unroll
      for (int m = 1; m <= 8; m <<= 1) {
        ps[rr] += __shfl_xor(ps[rr], m, 64);
        pd[rr] += __shfl_xor(pd[rr], m, 64);
      }
    }
    if (r == 0) {
#pragma unroll
      for (int rr = 0; rr < 4; ++rr) {
        es[rowbase + g * 4 + rr] = ps[rr];
        ed[rowbase + g * 4 + rr] = pd[rr];
      }
    }
  }
}

// ---------------------------------------------------------------------------
// h = xb @ W via MFMA 16x16x32 bf16 (layers 1,2). No LDS.
// ---------------------------------------------------------------------------
__global__ __launch_bounds__(256) void k_gemm_e(
    const unsigned short* __restrict__ xb, const unsigned short* __restrict__ WT,
    const float* __restrict__ asrc, const float* __restrict__ adst,
    unsigned short* __restrict__ hb, float* __restrict__ es,
    float* __restrict__ ed) {
  int tid = threadIdx.x;
  int w = tid >> 6, l = tid & 63;
  long rowbase = (long)blockIdx.x * 64 + w * 16;
  int r = l & 15, g = l >> 4;

  f32x4 acc[8];
#pragma unroll
  for (int n = 0; n < 8; ++n) acc[n] = {0.f, 0.f, 0.f, 0.f};

#pragma unroll
  for (int ks = 0; ks < 4; ++ks) {
    bf16x8 a = *(const bf16x8*)&xb[(rowbase + r) * 128 + ks * 32 + g * 8];
#pragma unroll
    for (int n = 0; n < 8; ++n) {
      bf16x8 bfr = *(const bf16x8*)&WT[(n * 16 + r) * 128 + ks * 32 + g * 8];
      acc[n] = __builtin_amdgcn_mfma_f32_16x16x32_bf16(a, bfr, acc[n], 0, 0, 0);
    }
  }

  float ps[4] = {0.f, 0.f, 0.f, 0.f};
  float pd[4] = {0.f, 0.f, 0.f, 0.f};
#pragma unroll
  for (int n = 0; n < 8; ++n) {
    float sa = asrc[n * 16 + r];
    float sd = adst[n * 16 + r];
#pragma unroll
    for (int rr = 0; rr < 4; ++rr) {
      float v = acc[n][rr];
      hb[(rowbase + g * 4 + rr) * 128 + n * 16 + r] = f2b(v);
      ps[rr] = fmaf(v, sa, ps[rr]);
      pd[rr] = fmaf(v, sd, pd[rr]);
    }
  }
#pragma unroll
  for (int rr = 0; rr < 4; ++rr) {
#pragma unroll
    for (int m = 1; m <= 8; m <<= 1) {
      ps[rr] += __shfl_xor(ps[rr], m, 64);
      pd[rr] += __shfl_xor(pd[rr], m, 64);
    }
  }
  if (r == 0) {
#pragma unroll
    for (int rr = 0; rr < 4; ++rr) {
      es[rowbase + g * 4 + rr] = ps[rr];
      ed[rowbase + g * 4 + rr] = pd[rr];
    }
  }
}

#define CEX(a, b, up)                         \
  do {                                        \
    if (((a) > (b)) == (up)) {                \
      unsigned long long _t = (a);            \
      (a) = (b);                              \
      (b) = _t;                               \
    }                                         \
  } while (0)

// ---------------------------------------------------------------------------
// Fused sort + scan + coeffs + chunk-sums + chunk-prefix + sorted-h emission.
// grid (NB, 4), 512 threads. C12 written interleaved (c1,c2) float2.
// ---------------------------------------------------------------------------
__global__ __launch_bounds__(512) void k_scpfx(
    const float* __restrict__ es, const float* __restrict__ ed,
    const unsigned short* __restrict__ hb, float2* __restrict__ e12,
    int* __restrict__ kcut, float2* __restrict__ ab, float2* __restrict__ C12,
    unsigned short* __restrict__ hs) {
  __shared__ unsigned long long keys[NP];      // 8192 B, live A..D
  __shared__ float smem[(NC + 1) * 64];        // 32256 B overlay: sc | s1,s2
  __shared__ float2 wtot[8];
  float2* sc = (float2*)smem;                  // 1000 float2 (B..C)
  float (*s1)[32] = (float(*)[32])smem;        // 126x32 (D..F)
  float (*s2)[32] = (float(*)[32])(smem + (NC + 1) * 32);
  int tid = threadIdx.x, b = blockIdx.x, dq = blockIdx.y;

  // ---- A: load + u64 bitonic sort ----
  for (int i = tid; i < NP; i += 512) {
    unsigned long long kk;
    if (i < NN) {
      kk = ((unsigned long long)tkey(es[b * NN + i]) << 32) | (unsigned)i;
    } else {
      kk = (0xFF800000ull << 32) | (unsigned)i;  // tkey(+INF) pad
    }
    keys[i] = kk;
  }
  __syncthreads();
  int i0 = tid * 2;
  {
    unsigned long long q0 = keys[i0], q1 = keys[i0 + 1];
    CEX(q0, q1, (i0 & 2) == 0);
    keys[i0] = q0; keys[i0 + 1] = q1;
  }
  __syncthreads();
  for (int k = 4; k <= NP; k <<= 1) {
    for (int j = k >> 1; j >= 2; j >>= 1) {
      int i = ((tid & ~(j - 1)) << 1) | (tid & (j - 1));
      int ixj = i | j;
      bool up = ((i & k) == 0);
      unsigned long long a = keys[i], c = keys[ixj];
      if ((a > c) == up) { keys[i] = c; keys[ixj] = a; }
      __syncthreads();
    }
    {
      unsigned long long q0 = keys[i0], q1 = keys[i0 + 1];
      CEX(q0, q1, (i0 & k) == 0);
      keys[i0] = q0; keys[i0 + 1] = q1;
    }
    __syncthreads();
  }

  // ---- B: decode + hierarchical scan of (e1,e2) -> sc ----
  float2 f0 = make_float2(0.f, 0.f), f1 = make_float2(0.f, 0.f);
  {
    unsigned long long k0 = keys[i0], k1 = keys[i0 + 1];
    if (i0 < NN) {
      float s = tdec((unsigned)(k0 >> 32));
      f0.x = __expf(s);
      f0.y = __expf(0.2f * s);
      if (dq == 0) e12[b * NN + i0] = f0;
    }
    if (i0 + 1 < NN) {
      float s = tdec((unsigned)(k1 >> 32));
      f1.x = __expf(s);
      f1.y = __expf(0.2f * s);
      if (dq == 0) e12[b * NN + i0 + 1] = f1;
    }
  }
  int lane = tid & 63, wid = tid >> 6;
  float tx = f0.x + f1.x, ty = f0.y + f1.y;
  float ix = tx, iy = ty;
#pragma unroll
  for (int dlt = 1; dlt < 64; dlt <<= 1) {
    float ox = __shfl_up(ix, dlt, 64);
    float oy = __shfl_up(iy, dlt, 64);
    if (lane >= dlt) { ix += ox; iy += oy; }
  }
  if (lane == 63) wtot[wid] = make_float2(ix, iy);
  __syncthreads();
  float bx = 0.f, by = 0.f;
#pragma unroll
  for (int ww = 0; ww < 8; ++ww) {
    if (ww < wid) {
      float2 t = wtot[ww];
      bx += t.x;
      by += t.y;
    }
  }
  float exx = bx + ix - tx, eyy = by + iy - ty;  // exclusive at i0
  float in0x = exx + f0.x, in0y = eyy + f0.y;
  if (i0 < NN) sc[i0] = make_float2(in0x, in0y);
  if (i0 + 1 < NN) sc[i0 + 1] = make_float2(in0x + f1.x, in0y + f1.y);
  __syncthreads();

  // ---- C: per-target coefficients (dq==0 only) ----
  if (dq == 0) {
    float s1tot = sc[NN - 1].x;
    for (int i = tid; i < NN; i += 512) {
      float di = ed[b * NN + i];
      unsigned tt = tkey(-di);
      int lo = 0, hi = NP;
      while (lo < hi) {
        int mid = (lo + hi) >> 1;
        if ((unsigned)(keys[mid] >> 32) <= tt) lo = mid + 1; else hi = mid;
      }
      int k = lo;  // #{s_j <= t_i} <= NN (pads are +INF)
      float p1 = (k > 0) ? sc[k - 1].x : 0.f;
      float p2 = (k > 0) ? sc[k - 1].y : 0.f;
      float Ed = __expf(di);
      float Ed2 = __expf(0.2f * di);
      float den = fmaf(Ed, s1tot - p1, Ed2 * p2);
      kcut[b * NN + i] = k;
      ab[b * NN + i] = make_float2(Ed / den, Ed2 / den);
    }
  }
  __syncthreads();  // sc dead after this; s1/s2 may overwrite

  // ---- D: chunk gather via LDS keys; write hs + chunk sums ----
  int d = tid & 31;
  int cl = tid >> 5;  // chunk lane 0..15
  int dglob = dq * 32 + d;
  for (int c = cl; c < NC; c += 16) {
    float v1 = 0.f, v2 = 0.f;
#pragma unroll
    for (int u = 0; u < CS; ++u) {
      int j = c * CS + u;
      unsigned long long kk = keys[j];
      int p = (int)(unsigned)kk;
      float s = tdec((unsigned)(kk >> 32));
      float e1 = __expf(s), e2 = __expf(0.2f * s);
      unsigned short hraw = hb[((long)b * NN + p) * HD + dglob];
      hs[((long)b * NN + j) * HD + dglob] = hraw;
      float hv = b2f(hraw);
      v1 = fmaf(e1, hv, v1);
      v2 = fmaf(e2, hv, v2);
    }
    s1[c][d] = v1;
    s2[c][d] = v2;
  }
  __syncthreads();

  // ---- E: serial exclusive chunk prefix (+ totals) ----
  if (tid < 32) {
    float r = 0.f;
    for (int c = 0; c < NC; ++c) {
      float v = s1[c][tid];
      s1[c][tid] = r;
      r += v;
    }
    s1[NC][tid] = r;
  } else if (tid < 64) {
    int dd = tid - 32;
    float r = 0.f;
    for (int c = 0; c < NC; ++c) {
      float v = s2[c][dd];
      s2[c][dd] = r;
      r += v;
    }
    s2[NC][dd] = r;
  }
  __syncthreads();

  // ---- F: coalesced interleaved C12 store ----
  long basec = (long)b * (NC + 1) * HD + dq * 32;
  for (int i = tid; i < (NC + 1) * 32; i += 512) {
    int c = i >> 5, dd = i & 31;
    C12[basec + (long)c * HD + dd] = make_float2(s1[c][dd], s2[c][dd]);
  }
}

// ---------------------------------------------------------------------------
// out[i] = a_i*(T1 - C1[c_i] - res1) + b_i*(C2[c_i] + res2) + bias.
// C12 interleaved; residual reads hs (sorted-order, streaming).
// ---------------------------------------------------------------------------
template <bool APPLY_BN>
__global__ __launch_bounds__(128) void k_out(
    const unsigned short* __restrict__ hs, const float2* __restrict__ C12,
    const float2* __restrict__ e12, const int* __restrict__ kcut,
    const float2* __restrict__ ab, const float* __restrict__ bias,
    const float* __restrict__ bng, const float* __restrict__ bnb,
    const float* __restrict__ bnm, const float* __restrict__ bnv,
    float* __restrict__ xo, unsigned short* __restrict__ xbo) {
  int d = threadIdx.x, b = blockIdx.x;
  int i0 = blockIdx.y * 8;
  float T1 = C12[((long)b * (NC + 1) + NC) * HD + d].x;
  float bs = bias[d];
  float sc = 0.f, sh = 0.f;
  if (APPLY_BN) {
    float g = bng[d], bb = bnb[d], m = bnm[d], v = bnv[d];
    sc = g * rsqrtf(v + BN_EPS);
    sh = bb - m * sc;
  }
  for (int i = i0; i < i0 + 8; ++i) {
    int k = kcut[b * NN + i];
    float2 coeff = ab[b * NN + i];
    int c = k >> 3;
    float2 base12 = C12[((long)b * (NC + 1) + c) * HD + d];
    float p1 = 0.f, p2 = 0.f;
    for (int j = c * CS; j < k; ++j) {
      float hv = b2f(hs[((long)b * NN + j) * HD + d]);
      float2 e = e12[b * NN + j];
      p1 = fmaf(e.x, hv, p1);
      p2 = fmaf(e.y, hv, p2);
    }
    float val = fmaf(coeff.x, T1 - base12.x - p1,
                     fmaf(coeff.y, base12.y + p2, bs));
    long off = ((long)b * NN + i) * HD + d;
    if (APPLY_BN) {
      xbo[off] = f2b(fmaxf(fmaf(val, sc, sh), 0.f));
    } else {
      xo[off] = val;
    }
  }
}

extern "C" void kernel_launch(void* const* d_in, const int* in_sizes, int n_in,
                              void* d_out, int out_size, void* d_ws,
                              size_t ws_size, hipStream_t stream) {
  const float* locs = (const float*)d_in[0];
  const float* le_W0 = (const float*)d_in[1];
  const float* le_b0 = (const float*)d_in[2];
  const float* le_W1 = (const float*)d_in[3];
  const float* le_b1 = (const float*)d_in[4];
  const float* le_bn_g = (const float*)d_in[5];
  const float* le_bn_b = (const float*)d_in[6];
  const float* le_bn_m = (const float*)d_in[7];
  const float* le_bn_v = (const float*)d_in[8];
  const float* le_Wo = (const float*)d_in[9];
  const float* le_bo = (const float*)d_in[10];
  const float* gat_W = (const float*)d_in[11];
  const float* gat_asrc = (const float*)d_in[12];
  const float* gat_adst = (const float*)d_in[13];
  const float* gat_b = (const float*)d_in[14];
  const float* bn_g = (const float*)d_in[15];
  const float* bn_b = (const float*)d_in[16];
  const float* bn_m = (const float*)d_in[17];
  const float* bn_v = (const float*)d_in[18];

  float* out = (float*)d_out;                          // final f32 output
  unsigned short* hb = (unsigned short*)d_ws;          // 8,192,000 bf16
  unsigned short* hs = hb + 8192000;                   // 8,192,000 bf16
  unsigned short* xb = hs + 8192000;                   // 8,192,000 bf16
  unsigned short* WT = xb + 8192000;                   // 49,152 bf16
  unsigned short* W1T = WT + 49152;                    // 4,096 bf16
  unsigned short* WoWgT = W1T + 4096;                  // 8,192 bf16
  float* biash = (float*)(WoWgT + 8192 + 32);          // 128 f32
  float2* C12 = (float2*)(biash + 128 + 32);           // 1,032,192 float2
  float* es = (float*)(C12 + 1032192);
  float* ed = es + 64000;
  float2* e12 = (float2*)(ed + 64000);                 // 64,000 float2
  float2* ab = e12 + 64000;                            // 64,000 float2
  int* kcut = (int*)(ab + 64000);
  // total ≈ 59 MB << ws

  k_wprep<<<241, 256, 0, stream>>>(gat_W, le_W1, le_Wo, le_bo, WT, W1T, WoWgT,
                                   biash);
  for (int l = 0; l < 3; ++l) {
    if (l == 0) {
      k_embed_gemm<<<1000, 256, 0, stream>>>(
          locs, le_W0, le_b0, le_b1, le_bn_g, le_bn_b, le_bn_m, le_bn_v, W1T,
          WoWgT, biash, gat_asrc, gat_adst, hb, es, ed);
    } else {
      k_gemm_e<<<1000, 256, 0, stream>>>(xb, WT + l * 16384,
                                         gat_asrc + l * 128,
                                         gat_adst + l * 128, hb, es, ed);
    }
    k_scpfx<<<dim3(NB, 4), 512, 0, stream>>>(es, ed, hb, e12, kcut, ab, C12,
                                             hs);
    if (l < 2) {
      k_out<true><<<dim3(NB, NC), 128, 0, stream>>>(
          hs, C12, e12, kcut, ab, gat_b + l * 128, bn_g + l * 128,
          bn_b + l * 128, bn_m + l * 128, bn_v + l * 128, nullptr, xb);
    } else {
      k_out<false><<<dim3(NB, NC), 128, 0, stream>>>(
          hs, C12, e12, kcut, ab, gat_b + 2 * 128, nullptr, nullptr, nullptr,
          nullptr, out, nullptr);
    }
  }
}